// Round 10
// baseline (2792.706 us; speedup 1.0000x reference)
//
#include <hip/hip_runtime.h>
#include <cstdint>
#include <cstddef>

#define B_   32
#define SE_  256
#define HE_  512
#define HD_  1024
#define ED_  256
#define N_   8192
#define T_   20
#define KE_  1024
#define VE_  1024
#define MD_  256
#define EIN_ 768
#define NEG_   (-10000000.0f)
#define MAXV_  (1000000000.0f)
#define EPS_   (1e-8f)
#define SPARSE_ 0.8f
#define GATE_  0.78f   // bf16-safe gate; pass-2 recomputes exact f32, false positives harmless

#define NLOGB (N_/16)

// output offsets (floats)
#define O_IDS  (B_*T_*N_)            // 5242880
#define O_KEY  (O_IDS + B_*T_)       // 5243520
#define O_VAL  (O_KEY + B_*KE_)      // 5276288

typedef __attribute__((ext_vector_type(8))) short short8;
typedef __attribute__((ext_vector_type(4))) float floatx4;

__device__ __forceinline__ float sigf(float v) { return 1.0f / (1.0f + expf(-v)); }

__device__ __forceinline__ short f2bf(float f) {
    union { float f; unsigned u; } v; v.f = f;
    unsigned r = v.u + 0x7FFFu + ((v.u >> 16) & 1u);   // RNE
    return (short)(r >> 16);
}
__device__ __forceinline__ short8 pack8(const float4 a, const float4 b) {
    short8 r;
    r[0]=f2bf(a.x); r[1]=f2bf(a.y); r[2]=f2bf(a.z); r[3]=f2bf(a.w);
    r[4]=f2bf(b.x); r[5]=f2bf(b.y); r[6]=f2bf(b.z); r[7]=f2bf(b.w);
    return r;
}

// ordered-float mapping: monotone uint, handles negatives (no NaN expected)
__device__ __forceinline__ unsigned ord_f(float f) {
    unsigned u = __float_as_uint(f);
    return (u & 0x80000000u) ? ~u : (u | 0x80000000u);
}

// Bool-mask layout probe (verified in an earlier session): int32 vs packed byte.
__device__ __forceinline__ bool mask_is_b8(const void* p) {
    unsigned u = *(const unsigned*)p;
    return u > 0xFFu;
}
__device__ __forceinline__ bool mask_at(const void* p, int idx, bool b8) {
    return b8 ? (((const unsigned char*)p)[idx] != 0)
              : (((const int*)p)[idx] != 0);
}

// ---------------------------------------------------------------- init
__global__ __launch_bounds__(256) void k_init(
    const float* __restrict__ hidden, const float* __restrict__ cell,
    const float* __restrict__ enc, const void* __restrict__ encmask,
    float* __restrict__ h, float* __restrict__ c, float* __restrict__ x,
    float* __restrict__ lmask, float* __restrict__ sent, float* __restrict__ pad,
    float* __restrict__ key_run, float* __restrict__ val_sim, float* __restrict__ rowmax,
    unsigned long long* __restrict__ amax)
{
    int idx = blockIdx.x * 256 + threadIdx.x;   // 0 .. 262143
    lmask[idx] = 0.0f;
    if (idx < T_ * B_) amax[idx] = 0ULL;        // packed argmax slots (ordered 0 = most-negative float)
    if (idx < B_ * HD_) {
        int b = idx >> 10, j = idx & 1023;
        int d = j >> 9, e = j & 511;
        h[idx] = hidden[((size_t)d * B_ + b) * HE_ + e];
        c[idx] = cell  [((size_t)d * B_ + b) * HE_ + e];
        key_run[idx] = -1e30f;
        val_sim[idx] = 0.0f;
        rowmax[idx] = 0.0f;                    // atomicMax target (non-negative)
    }
    if (idx < B_ * EIN_) x[idx] = 0.0f;
    if (idx < B_ * HE_) {
        int b = idx >> 9, e = idx & 511;
        sent[idx] = enc[(size_t)b * SE_ * HE_ + e];
    }
    if (idx < B_ * SE_) {
        bool b8 = mask_is_b8(encmask);
        pad[idx] = mask_at(encmask, idx, b8) ? 0.0f : -MAXV_;
    }
}

// ---------------------------------------------------------------- row norms
__global__ __launch_bounds__(256) void k_norms(
    const float* __restrict__ mem_k, const float* __restrict__ mem_v,
    float* __restrict__ normk, float* __restrict__ normv)
{
    int lane = threadIdx.x & 63;
    int wave = (blockIdx.x * 256 + threadIdx.x) >> 6;   // 0..1023
    for (int row = wave; row < 2 * B_ * KE_; row += 1024) {
        const float* base = (row < B_ * KE_) ? (mem_k + (size_t)row * MD_)
                                             : (mem_v + (size_t)(row - B_ * KE_) * MD_);
        float4 v = ((const float4*)base)[lane];
        float s = v.x*v.x + v.y*v.y + v.z*v.z + v.w*v.w;
        for (int m = 32; m; m >>= 1) s += __shfl_xor(s, m, 64);
        if (lane == 0) {
            if (row < B_ * KE_) normk[row] = sqrtf(s);
            else                normv[row - B_ * KE_] = sqrtf(s);
        }
    }
}

// ---------------------------------------------------------------- rowmax via bf16 MFMA
__global__ __launch_bounds__(256) void k_rowmax_mfma(
    const float* __restrict__ mem_k, const float* __restrict__ mem_v,
    const float* __restrict__ normk, const float* __restrict__ normv,
    float* __restrict__ rowmax)
{
    __shared__ __align__(16) short Vs[64 * 256];   // 32768 B, swizzled
    const int tid = threadIdx.x, lane = tid & 63, w = tid >> 6;
    const int kt = blockIdx.x, vseg = blockIdx.y, b = blockIdx.z;
    const int rowbase = kt * 128 + w * 32;
    const int lrow = lane & 15, lq = lane >> 4;   // lq in 0..3

    float nk[2][4];
    #pragma unroll
    for (int rg = 0; rg < 2; ++rg)
        #pragma unroll
        for (int reg = 0; reg < 4; ++reg)
            nk[rg][reg] = normk[b * KE_ + rowbase + rg * 16 + lq * 4 + reg];

    short8 af[2][8];
    #pragma unroll
    for (int rg = 0; rg < 2; ++rg) {
        const float* arow = mem_k + ((size_t)(b * KE_ + rowbase + rg * 16 + lrow)) * MD_;
        #pragma unroll
        for (int kc = 0; kc < 8; ++kc) {
            const float* p = arow + kc * 32 + lq * 8;
            float4 f0 = *(const float4*)p;
            float4 f1 = *(const float4*)(p + 4);
            af[rg][kc] = pack8(f0, f1);
        }
    }

    float rmax[2][4];
    #pragma unroll
    for (int rg = 0; rg < 2; ++rg)
        #pragma unroll
        for (int reg = 0; reg < 4; ++reg) rmax[rg][reg] = -1e30f;

    for (int vs = vseg * 4; vs < vseg * 4 + 4; ++vs) {
        __syncthreads();
        #pragma unroll
        for (int i = 0; i < 8; ++i) {
            int lin = tid + i * 256;             // 0..2047 = 64 rows x 32 groups
            int r = lin >> 5, cg = lin & 31;
            const float* p = mem_v + ((size_t)(b * VE_ + vs * 64 + r)) * MD_ + cg * 8;
            float4 f0 = *(const float4*)p;
            float4 f1 = *(const float4*)(p + 4);
            int byt = (r * 512 + cg * 16) ^ ((r & 7) << 4);
            *(short8*)((char*)Vs + byt) = pack8(f0, f1);
        }
        __syncthreads();

        for (int vsub = 0; vsub < 4; ++vsub) {
            int vrow = vsub * 16 + lrow;
            float nv = normv[b * VE_ + vs * 64 + vrow];
            short8 bfr[8];
            #pragma unroll
            for (int kc = 0; kc < 8; ++kc) {
                int byt = (vrow * 512 + kc * 64 + lq * 16) ^ ((vrow & 7) << 4);
                bfr[kc] = *(const short8*)((char*)Vs + byt);
            }
            #pragma unroll
            for (int rg = 0; rg < 2; ++rg) {
                floatx4 acc = {0.0f, 0.0f, 0.0f, 0.0f};
                #pragma unroll
                for (int kc = 0; kc < 8; ++kc)
                    acc = __builtin_amdgcn_mfma_f32_16x16x32_bf16(af[rg][kc], bfr[kc], acc, 0, 0, 0);
                #pragma unroll
                for (int reg = 0; reg < 4; ++reg) {
                    float cs = acc[reg] / fmaxf(nk[rg][reg] * nv, EPS_);
                    rmax[rg][reg] = fmaxf(rmax[rg][reg], cs);
                }
            }
        }
    }
    #pragma unroll
    for (int rg = 0; rg < 2; ++rg)
        #pragma unroll
        for (int reg = 0; reg < 4; ++reg) {
            float v = rmax[rg][reg];
            v = fmaxf(v, __shfl_xor(v, 1, 64));
            v = fmaxf(v, __shfl_xor(v, 2, 64));
            v = fmaxf(v, __shfl_xor(v, 4, 64));
            v = fmaxf(v, __shfl_xor(v, 8, 64));
            if (lrow == 0) {
                int* p = (int*)&rowmax[(size_t)b * KE_ + rowbase + rg * 16 + lq * 4 + reg];
                atomicMax(p, __float_as_int(fmaxf(v, 0.0f)));   // non-neg: int order == float order
            }
        }
}

// ---------------------------------------------------------------- wave dot helper (global row x LDS vec)
__device__ __forceinline__ float wave_dot(const float* __restrict__ row, const float* vl, int quads)
{
    int lane = threadIdx.x & 63;
    float s = 0.0f;
    for (int q = lane; q < quads; q += 64) {
        float4 a = ((const float4*)row)[q];
        float4 x = ((const float4*)vl)[q];
        s = fmaf(a.x, x.x, s); s = fmaf(a.y, x.y, s);
        s = fmaf(a.z, x.z, s); s = fmaf(a.w, x.w, s);
    }
    for (int m = 32; m; m >>= 1) s += __shfl_xor(s, m, 64);
    return s;
}

// ---------------------------------------------------------------- COMBINED: gates_t GEMM+LSTM (blocks 0-511) || ksim_{t-1} (blocks 512-1023)
__global__ __launch_bounds__(256) void k_gates_ksim(
    const float* __restrict__ x, const float* __restrict__ W_ih,
    const float* __restrict__ h_in, const float* __restrict__ W_hh,
    const float* __restrict__ b_ih, const float* __restrict__ b_hh,
    float* __restrict__ c_st, float* __restrict__ h_out,
    const float* __restrict__ mqg, const float* __restrict__ mem_k,
    const float* __restrict__ normk, float* __restrict__ key_run, int do_ksim)
{
    __shared__ __align__(16) float Xs[32 * 256];
    __shared__ float red[8][32][17];               // gates role; ksim role aliases Xs
    const int tid = threadIdx.x;

    if (blockIdx.x >= 512) {
        // ======== ksim role (identical math to k_ksim) ========
        if (!do_ksim) return;
        float* mql  = Xs;                          // 256
        float* red2 = Xs + 256;                    // 256
        const int u = blockIdx.x - 512;
        const int kt = u & 15, b = u >> 4;
        const int lane = tid & 63, w = tid >> 6;
        float mv = mqg[(size_t)b * MD_ + tid];
        mql[tid] = mv;
        red2[tid] = mv * mv;
        __syncthreads();
        for (int s = 128; s > 0; s >>= 1) { if (tid < s) red2[tid] += red2[tid + s]; __syncthreads(); }
        float nmq = sqrtf(red2[0]);
        int base = kt * 64 + w * 16;
        for (int i = 0; i < 16; ++i) {
            int k = base + i;
            float num = wave_dot(mem_k + ((size_t)b * KE_ + k) * MD_, mql, MD_ / 4);
            if (lane == 0) {
                float cs = num / fmaxf(nmq * normk[b * KE_ + k], EPS_);
                float o = key_run[b * KE_ + k];
                key_run[b * KE_ + k] = fmaxf(o, cs);
            }
        }
        return;
    }

    // ======== gates role ========
    const int kg = tid & 15, jg = (tid >> 4) & 3, bg = tid >> 6;
    const int ch0 = blockIdx.x * 2;                // 2 channels per block

    float acc[2][8];
    #pragma unroll
    for (int jv = 0; jv < 2; ++jv)
        #pragma unroll
        for (int bv = 0; bv < 8; ++bv) acc[jv][bv] = 0.0f;

    for (int k0 = 0; k0 < EIN_ + HD_; k0 += 256) {
        const bool second = (k0 >= EIN_);
        const float* Xsrc = second ? h_in : x;
        const float* Wsrc = second ? W_hh : W_ih;
        const int srcK = second ? HD_ : EIN_;
        const int ks = second ? (k0 - EIN_) : k0;
        __syncthreads();
        #pragma unroll
        for (int i = 0; i < 8; ++i) {
            int lin = tid + i * 256;
            int bb = lin >> 6, q = lin & 63;
            *(float4*)&Xs[bb * 256 + q * 4] = *(const float4*)(Xsrc + (size_t)bb * srcK + ks + q * 4);
        }
        __syncthreads();
        #pragma unroll
        for (int qq = 0; qq < 4; ++qq) {
            const int qc = kg + qq * 16;
            float4 wv[2];
            #pragma unroll
            for (int jv = 0; jv < 2; ++jv) {
                int row = jg * HD_ + ch0 + jv;     // jg = gate, jv = channel
                wv[jv] = *(const float4*)(Wsrc + (size_t)row * srcK + ks + qc * 4);
            }
            #pragma unroll
            for (int bv = 0; bv < 8; ++bv) {
                float4 x4 = *(const float4*)&Xs[(bg * 8 + bv) * 256 + qc * 4];
                #pragma unroll
                for (int jv = 0; jv < 2; ++jv) {
                    acc[jv][bv] = fmaf(wv[jv].x, x4.x, acc[jv][bv]);
                    acc[jv][bv] = fmaf(wv[jv].y, x4.y, acc[jv][bv]);
                    acc[jv][bv] = fmaf(wv[jv].z, x4.z, acc[jv][bv]);
                    acc[jv][bv] = fmaf(wv[jv].w, x4.w, acc[jv][bv]);
                }
            }
        }
    }
    #pragma unroll
    for (int jv = 0; jv < 2; ++jv)
        #pragma unroll
        for (int bv = 0; bv < 8; ++bv)
            red[jg * 2 + jv][bg * 8 + bv][kg] = acc[jv][bv];
    __syncthreads();
    if (tid < 64) {                                // 2 ch x 32 b
        const int c2 = tid >> 5, b = tid & 31;
        float g4[4];
        #pragma unroll
        for (int gate = 0; gate < 4; ++gate) {
            float s = 0.0f;
            #pragma unroll
            for (int k = 0; k < 16; ++k) s += red[gate * 2 + c2][b][k];
            int row = gate * HD_ + ch0 + c2;
            g4[gate] = s + b_ih[row] + b_hh[row];
        }
        int idx = b * HD_ + ch0 + c2;
        float c1 = sigf(g4[1]) * c_st[idx] + sigf(g4[0]) * tanhf(g4[2]);
        h_out[idx] = sigf(g4[3]) * tanhf(c1);
        c_st[idx] = c1;
    }
}

// ---------------------------------------------------------------- mlp1 relu (256 blocks x 4 j)
__global__ __launch_bounds__(256) void k_mlp1(
    const float* __restrict__ X, const float* __restrict__ W,
    const float* __restrict__ bias, float* __restrict__ out)
{
    __shared__ __align__(16) float Xs[32 * 256];
    __shared__ float red[4][32][17];               // 8.7 KB
    const int tid = threadIdx.x;
    const int kg = tid & 15, jg = (tid >> 4) & 3, bg = tid >> 6;
    const int jbase = blockIdx.x * 4;

    float acc[8];
    #pragma unroll
    for (int bv = 0; bv < 8; ++bv) acc[bv] = 0.0f;

    for (int k0 = 0; k0 < HD_; k0 += 256) {
        __syncthreads();
        #pragma unroll
        for (int i = 0; i < 8; ++i) {
            int lin = tid + i * 256;
            int bb = lin >> 6, q = lin & 63;
            *(float4*)&Xs[bb * 256 + q * 4] = *(const float4*)(X + (size_t)bb * HD_ + k0 + q * 4);
        }
        __syncthreads();
        #pragma unroll
        for (int qq = 0; qq < 4; ++qq) {
            const int qc = kg + qq * 16;
            float4 w4 = *(const float4*)(W + (size_t)(jbase + jg) * HD_ + k0 + qc * 4);
            #pragma unroll
            for (int bv = 0; bv < 8; ++bv) {
                float4 x4 = *(const float4*)&Xs[(bg * 8 + bv) * 256 + qc * 4];
                acc[bv] = fmaf(w4.x, x4.x, acc[bv]);
                acc[bv] = fmaf(w4.y, x4.y, acc[bv]);
                acc[bv] = fmaf(w4.z, x4.z, acc[bv]);
                acc[bv] = fmaf(w4.w, x4.w, acc[bv]);
            }
        }
    }
    #pragma unroll
    for (int bv = 0; bv < 8; ++bv)
        red[jg][bg * 8 + bv][kg] = acc[bv];
    __syncthreads();
    if (tid < 128) {                               // 4 j x 32 b
        int jjo = tid >> 5, b = tid & 31;
        float s = 0.0f;
        #pragma unroll
        for (int k = 0; k < 16; ++k) s += red[jjo][b][k];
        int jo = jbase + jjo;
        out[(size_t)b * HD_ + jo] = fmaxf(s + bias[jo], 0.0f);
    }
}

// ---------------------------------------------------------------- logits GEMM + lmask + packed-atomic argmax
__global__ __launch_bounds__(256) void k_logits(
    const float* __restrict__ hid, const float* __restrict__ W2,
    const float* __restrict__ b2, const float* __restrict__ lmask,
    float* __restrict__ lg_out, unsigned long long* __restrict__ amax_t)
{
    __shared__ __align__(16) float Xs[32 * 256];
    __shared__ float red[16][32][17];
    const int tid = threadIdx.x;
    const int kg = tid & 15, jg = (tid >> 4) & 3, bg = tid >> 6;
    const int jbase = blockIdx.x * 16;

    float acc[4][8];
    #pragma unroll
    for (int jv = 0; jv < 4; ++jv)
        #pragma unroll
        for (int bv = 0; bv < 8; ++bv) acc[jv][bv] = 0.0f;

    for (int k0 = 0; k0 < HD_; k0 += 256) {
        __syncthreads();
        #pragma unroll
        for (int i = 0; i < 8; ++i) {
            int lin = tid + i * 256;
            int bb = lin >> 6, q = lin & 63;
            *(float4*)&Xs[bb * 256 + q * 4] = *(const float4*)(hid + (size_t)bb * HD_ + k0 + q * 4);
        }
        __syncthreads();
        #pragma unroll
        for (int qq = 0; qq < 4; ++qq) {
            const int qc = kg + qq * 16;
            float4 wv[4];
            #pragma unroll
            for (int jv = 0; jv < 4; ++jv)
                wv[jv] = *(const float4*)(W2 + (size_t)(jbase + jg * 4 + jv) * HD_ + k0 + qc * 4);
            #pragma unroll
            for (int bv = 0; bv < 8; ++bv) {
                float4 x4 = *(const float4*)&Xs[(bg * 8 + bv) * 256 + qc * 4];
                #pragma unroll
                for (int jv = 0; jv < 4; ++jv) {
                    acc[jv][bv] = fmaf(wv[jv].x, x4.x, acc[jv][bv]);
                    acc[jv][bv] = fmaf(wv[jv].y, x4.y, acc[jv][bv]);
                    acc[jv][bv] = fmaf(wv[jv].z, x4.z, acc[jv][bv]);
                    acc[jv][bv] = fmaf(wv[jv].w, x4.w, acc[jv][bv]);
                }
            }
        }
    }
    #pragma unroll
    for (int jv = 0; jv < 4; ++jv)
        #pragma unroll
        for (int bv = 0; bv < 8; ++bv)
            red[jg * 4 + jv][bg * 8 + bv][kg] = acc[jv][bv];
    __syncthreads();
    for (int o = tid; o < 16 * B_; o += 256) {
        int jjo = o >> 5, b = o & 31;
        float s = 0.0f;
        #pragma unroll
        for (int k = 0; k < 16; ++k) s += red[jjo][b][k];
        int jo = jbase + jjo;
        s += b2[jo] + lmask[(size_t)b * N_ + jo];
        lg_out[(size_t)b * (T_ * N_) + jo] = s;
        red[jjo][b][16] = s;
    }
    __syncthreads();
    if (tid < 32) {
        int b = tid;
        float best = -1e38f; int bi = 0;
        #pragma unroll
        for (int jjo = 0; jjo < 16; ++jjo) {
            float v = red[jjo][b][16];
            if (v > best) { best = v; bi = jjo; }   // strict > keeps smallest j within block
        }
        // pack: ordered(value) in high 32, (N-1-idx) in low 32 — ties resolve to smallest idx
        unsigned long long packed =
            ((unsigned long long)ord_f(best) << 32) | (unsigned)(N_ - 1 - (jbase + bi));
        atomicMax(&amax_t[b], packed);
    }
}

// ---------------------------------------------------------------- attn pass 1 + argmax decode + lmask + q (merge folded in)
// grid (sc=8, b=32). Each block reads the 8-byte packed argmax slot (no scan),
// computes q = emb[nid]@dense_W^T into LDS (x8 redundant, cheap), then its 32-s chunk.
// Block sc==0 writes nidbuf / d_out ids / lmask updates.
__global__ __launch_bounds__(256) void k_attn1m(
    const unsigned long long* __restrict__ amax_t,
    const float* __restrict__ emb, const float* __restrict__ dense_W,
    const float* __restrict__ dense_b,
    const float* __restrict__ enc, const float* __restrict__ pad,
    float* __restrict__ d_out, int t, int* __restrict__ nidbuf,
    float* __restrict__ lmask, float* __restrict__ part)
{
    __shared__ __align__(16) float lab[ED_];
    __shared__ __align__(16) float ql[HE_];
    __shared__ float sc_l[32];
    __shared__ float wp_l[32];
    const int b = blockIdx.y, sc = blockIdx.x;
    const int tid = threadIdx.x, lane = tid & 63, w = tid >> 6;

    const int nid = N_ - 1 - (int)(amax_t[b] & 0xFFFFFFFFULL);
    if (sc == 0 && tid == 0) {
        nidbuf[b] = nid;
        d_out[O_IDS + (size_t)b * T_ + t] = (float)nid;
        lmask[(size_t)b * N_ + nid] = NEG_;
        lmask[(size_t)b * N_] = 0.0f;             // EOS unmask (covers nid==0 too)
    }
    lab[tid] = emb[(size_t)nid * ED_ + tid];
    __syncthreads();

    // ---- q = lab @ dense_W^T + dense_b  (2 rows/thread -> LDS)
    const float4* Lq = (const float4*)lab;
    #pragma unroll
    for (int jj = 0; jj < 2; ++jj) {
        int j = tid + jj * 256;
        const float4* Wq = (const float4*)(dense_W + (size_t)j * ED_);
        float s0 = 0.0f, s1 = 0.0f, s2 = 0.0f, s3 = 0.0f;
        #pragma unroll
        for (int q = 0; q < 64; q += 4) {
            float4 w0 = Wq[q],   x0 = Lq[q];
            float4 w1 = Wq[q+1], x1 = Lq[q+1];
            float4 w2 = Wq[q+2], x2 = Lq[q+2];
            float4 w3 = Wq[q+3], x3 = Lq[q+3];
            s0 = fmaf(w0.x,x0.x,s0); s0 = fmaf(w0.y,x0.y,s0); s0 = fmaf(w0.z,x0.z,s0); s0 = fmaf(w0.w,x0.w,s0);
            s1 = fmaf(w1.x,x1.x,s1); s1 = fmaf(w1.y,x1.y,s1); s1 = fmaf(w1.z,x1.z,s1); s1 = fmaf(w1.w,x1.w,s1);
            s2 = fmaf(w2.x,x2.x,s2); s2 = fmaf(w2.y,x2.y,s2); s2 = fmaf(w2.z,x2.z,s2); s2 = fmaf(w2.w,x2.w,s2);
            s3 = fmaf(w3.x,x3.x,s3); s3 = fmaf(w3.y,x3.y,s3); s3 = fmaf(w3.z,x3.z,s3); s3 = fmaf(w3.w,x3.w,s3);
        }
        ql[j] = dense_b[j] + ((s0 + s1) + (s2 + s3));
    }
    __syncthreads();

    // ---- scores for this 32-s chunk
    #pragma unroll
    for (int i = 0; i < 8; ++i) {
        int sl = w + i * 4;
        int s = sc * 32 + sl;
        float v = wave_dot(enc + ((size_t)b * SE_ + s) * HE_, ql, HE_ / 4);
        if (lane == 0) sc_l[sl] = v + pad[b * SE_ + s];
    }
    __syncthreads();

    float m = -1e38f;
    #pragma unroll
    for (int i = 0; i < 32; ++i) m = fmaxf(m, sc_l[i]);
    if (tid < 32) wp_l[tid] = expf(sc_l[tid] - m);
    __syncthreads();
    float esum = 0.0f;
    #pragma unroll
    for (int i = 0; i < 32; ++i) esum += wp_l[i];

    float a0 = 0.0f, a1 = 0.0f;
    for (int i = 0; i < 32; ++i) {
        float wv = wp_l[i];
        const float* er = enc + ((size_t)b * SE_ + sc * 32 + i) * HE_;
        a0 = fmaf(wv, er[tid], a0);
        a1 = fmaf(wv, er[tid + 256], a1);
    }
    float* pb = part + ((size_t)b * 8 + sc) * 516;
    pb[tid] = a0;
    pb[256 + tid] = a1;
    if (tid == 0) { pb[512] = m; pb[513] = esum; }
}

// ---------------------------------------------------------------- attn pass 2 + x build + mq = x@read_W^T (grid 4 x 32)
__global__ __launch_bounds__(256) void k_attn2read(
    const float* __restrict__ part, const float* __restrict__ sent,
    const int* __restrict__ nidbuf, const float* __restrict__ emb,
    const float* __restrict__ read_W, const float* __restrict__ read_b,
    float* __restrict__ xg, float* __restrict__ mqg)
{
    __shared__ float ms[8], es[8];
    __shared__ __align__(16) float xl[EIN_];
    const int qv = blockIdx.x, b = blockIdx.y;
    const int tid = threadIdx.x;
    if (tid < 8) {
        ms[tid] = part[((size_t)b * 8 + tid) * 516 + 512];
        es[tid] = part[((size_t)b * 8 + tid) * 516 + 513];
    }
    __syncthreads();
    float m = -1e38f;
    #pragma unroll
    for (int c = 0; c < 8; ++c) m = fmaxf(m, ms[c]);
    float scale[8];
    float denom = 0.0f;
    #pragma unroll
    for (int c = 0; c < 8; ++c) { scale[c] = expf(ms[c] - m); denom += es[c] * scale[c]; }
    float inv = 1.0f / denom;
    float a0 = 0.0f, a1 = 0.0f;
    #pragma unroll
    for (int c = 0; c < 8; ++c) {
        const float* pb = part + ((size_t)b * 8 + c) * 516;
        a0 = fmaf(scale[c], pb[tid], a0);
        a1 = fmaf(scale[c], pb[256 + tid], a1);
    }
    a0 *= inv; a1 *= inv;
    int nid = nidbuf[b];
    xl[tid]             = emb[(size_t)nid * ED_ + tid];
    xl[ED_ + tid]       = sent[(size_t)b * HE_ + tid]       + a0;
    xl[ED_ + 256 + tid] = sent[(size_t)b * HE_ + 256 + tid] + a1;
    __syncthreads();
    if (qv == 0) {
        float* xr = xg + (size_t)b * EIN_;
        xr[tid] = xl[tid]; xr[tid + 256] = xl[tid + 256]; xr[tid + 512] = xl[tid + 512];
    }
    // mq rows [qv*64, qv*64+64): 4 threads per row, quarter-K each
    const int r = qv * 64 + (tid >> 2), kq = tid & 3;
    const float4* Wq = (const float4*)(read_W + (size_t)r * EIN_ + kq * 192);
    const float4* xq = (const float4*)(xl + kq * 192);
    float s0 = 0.0f, s1 = 0.0f, s2 = 0.0f, s3 = 0.0f;
    #pragma unroll
    for (int q = 0; q < 48; q += 4) {
        float4 w0 = Wq[q],   v0 = xq[q];
        float4 w1 = Wq[q+1], v1 = xq[q+1];
        float4 w2 = Wq[q+2], v2 = xq[q+2];
        float4 w3 = Wq[q+3], v3 = xq[q+3];
        s0 = fmaf(w0.x,v0.x,s0); s0 = fmaf(w0.y,v0.y,s0); s0 = fmaf(w0.z,v0.z,s0); s0 = fmaf(w0.w,v0.w,s0);
        s1 = fmaf(w1.x,v1.x,s1); s1 = fmaf(w1.y,v1.y,s1); s1 = fmaf(w1.z,v1.z,s1); s1 = fmaf(w1.w,v1.w,s1);
        s2 = fmaf(w2.x,v2.x,s2); s2 = fmaf(w2.y,v2.y,s2); s2 = fmaf(w2.z,v2.z,s2); s2 = fmaf(w2.w,v2.w,s2);
        s3 = fmaf(w3.x,v3.x,s3); s3 = fmaf(w3.z,v3.z,s3); s3 = fmaf(w3.y,v3.y,s3); s3 = fmaf(w3.w,v3.w,s3);
    }
    float s = ((s0 + s1) + (s2 + s3));
    s += __shfl_xor(s, 1, 64);
    s += __shfl_xor(s, 2, 64);
    if (kq == 0) mqg[(size_t)b * MD_ + r] = s + read_b[r];
}

// ---------------------------------------------------------------- ksim standalone (final step drain) — grid (16 kt, 32 b)
__global__ __launch_bounds__(256) void k_ksim(
    const float* __restrict__ mqg,
    const float* __restrict__ mem_k, const float* __restrict__ normk,
    float* __restrict__ key_run)
{
    __shared__ __align__(16) float mql[MD_];
    __shared__ float red[256];
    const int b = blockIdx.y, kt = blockIdx.x;    // kt 0..15
    const int tid = threadIdx.x, lane = tid & 63, w = tid >> 6;
    float mv = mqg[(size_t)b * MD_ + tid];
    mql[tid] = mv;
    red[tid] = mv * mv;
    __syncthreads();
    for (int s = 128; s > 0; s >>= 1) { if (tid < s) red[tid] += red[tid + s]; __syncthreads(); }
    float nmq = sqrtf(red[0]);

    int base = kt * 64 + w * 16;
    for (int i = 0; i < 16; ++i) {
        int k = base + i;
        float num = wave_dot(mem_k + ((size_t)b * KE_ + k) * MD_, mql, MD_ / 4);
        if (lane == 0) {
            float cs = num / fmaxf(nmq * normk[b * KE_ + k], EPS_);
            float o = key_run[b * KE_ + k];
            key_run[b * KE_ + k] = fmaxf(o, cs);
        }
    }
}

// ---------------------------------------------------------------- key finalize + key_out
__global__ __launch_bounds__(256) void k_keyfinal(
    float* __restrict__ key_run, const void* __restrict__ kmask, float* __restrict__ d_out)
{
    int idx = blockIdx.x * 256 + threadIdx.x;    // 0..32767
    bool b8 = mask_is_b8(kmask);
    float v = key_run[idx];
    v = (v < 0.0f) ? 0.0f : v;
    key_run[idx] = v;
    d_out[O_KEY + idx] = mask_at(kmask, idx, b8) ? v : -1.0f;
}

// ---------------------------------------------------------------- val contributions (rows gated by bf16 rowmax; exact f32 recompute)
__global__ __launch_bounds__(256) void k_val(
    const float* __restrict__ rowmax, const float* __restrict__ mem_k, const float* __restrict__ mem_v,
    const float* __restrict__ normk, const float* __restrict__ normv,
    const float* __restrict__ key_sim, float* __restrict__ val_sim)
{
    int idx = blockIdx.x * 256 + threadIdx.x;    // 0..32767 : (b,k)
    if (rowmax[idx] < GATE_) return;
    int b = idx >> 10;
    const float* krow = mem_k + (size_t)idx * MD_;
    float nk = normk[idx];
    float ks = key_sim[idx];
    float rm = -1e30f;
    for (int v = 0; v < VE_; ++v) {
        const float* vrow = mem_v + ((size_t)b * VE_ + v) * MD_;
        float d = 0.0f;
        for (int e = 0; e < MD_; ++e) d = fmaf(krow[e], vrow[e], d);
        float cs = d / fmaxf(nk * normv[b * VE_ + v], EPS_);
        rm = fmaxf(rm, cs);
    }
    float thr = fmaxf(rm, SPARSE_);
    for (int v = 0; v < VE_; ++v) {
        const float* vrow = mem_v + ((size_t)b * VE_ + v) * MD_;
        float d = 0.0f;
        for (int e = 0; e < MD_; ++e) d = fmaf(krow[e], vrow[e], d);
        float cs = d / fmaxf(nk * normv[b * VE_ + v], EPS_);
        if (cs >= thr) atomicAdd(&val_sim[(size_t)b * VE_ + v], ks * cs);
    }
}

// ---------------------------------------------------------------- val_out
__global__ __launch_bounds__(256) void k_valout(
    const float* __restrict__ val_sim, const void* __restrict__ vmask, float* __restrict__ d_out)
{
    int idx = blockIdx.x * 256 + threadIdx.x;
    bool b8 = mask_is_b8(vmask);
    d_out[O_VAL + idx] = mask_at(vmask, idx, b8) ? val_sim[idx] : -1.0f;
}

// ================================================================ launch
extern "C" void kernel_launch(void* const* d_in, const int* in_sizes, int n_in,
                              void* d_out_v, int out_size, void* d_ws, size_t ws_size,
                              hipStream_t stream)
{
    const float* enc      = (const float*)d_in[0];
    const float* hidden   = (const float*)d_in[1];
    const float* cell     = (const float*)d_in[2];
    const void*  encmask  = d_in[4];
    const void*  kmask    = d_in[5];
    const float* mem_k    = (const float*)d_in[6];
    const void*  vmask    = d_in[7];
    const float* mem_v    = (const float*)d_in[8];
    const float* W_ih     = (const float*)d_in[9];
    const float* W_hh     = (const float*)d_in[10];
    const float* b_ih     = (const float*)d_in[11];
    const float* b_hh     = (const float*)d_in[12];
    const float* mlp_W1   = (const float*)d_in[13];
    const float* mlp_b1   = (const float*)d_in[14];
    const float* mlp_W2   = (const float*)d_in[15];
    const float* mlp_b2   = (const float*)d_in[16];
    const float* emb      = (const float*)d_in[17];
    const float* dense_W  = (const float*)d_in[18];
    const float* dense_b  = (const float*)d_in[19];
    const float* read_W   = (const float*)d_in[20];
    const float* read_b   = (const float*)d_in[21];
    float* d_out = (float*)d_out_v;
    float* ws = (float*)d_ws;

    float* hA      = ws;             // 32768
    float* hB      = ws + 32768;     // 32768
    float* c       = ws + 65536;     // 32768
    float* x       = ws + 98304;     // 24576
    float* hid     = ws + 122880;    // 32768
    float* lmask   = ws + 155648;    // 262144
    float* sent    = ws + 417792;    // 16384
    float* pad     = ws + 434176;    // 8192
    float* key_run = ws + 442368;    // 32768
    float* val_sim = ws + 475136;    // 32768
    float* normk   = ws + 507904;    // 32768
    float* normv   = ws + 540672;    // 32768
    float* rowmax  = ws + 573440;    // 32768
    int*   nidbuf  = (int*)(ws + 606208); // 64
    float* mqg     = ws + 606272;    // 8192
    float* part    = ws + 630848;    // 132096
    unsigned long long* amax = (unsigned long long*)(ws + 762944); // T_*B_=640 slots (5 KB)
    // total ≈ 764224 floats ≈ 2.92 MB

    k_init<<<1024, 256, 0, stream>>>(hidden, cell, enc, encmask, hA, c, x, lmask, sent, pad,
                                     key_run, val_sim, rowmax, amax);
    k_norms<<<256, 256, 0, stream>>>(mem_k, mem_v, normk, normv);
    k_rowmax_mfma<<<dim3(8, 4, 32), 256, 0, stream>>>(mem_k, mem_v, normk, normv, rowmax);

    const float* hin = hA;
    float* hout = hB;
    for (int t = 0; t < T_; ++t) {
        // gates_t co-launched with ksim_{t-1} (independent; both ready after attn2read_{t-1})
        k_gates_ksim<<<1024, 256, 0, stream>>>(x, W_ih, hin, W_hh, b_ih, b_hh, c, hout,
                                               mqg, mem_k, normk, key_run, t > 0 ? 1 : 0);
        k_mlp1<<<HD_ / 4, 256, 0, stream>>>(hout, mlp_W1, mlp_b1, hid);
        k_logits<<<N_ / 16, 256, 0, stream>>>(hid, mlp_W2, mlp_b2, lmask,
                                              d_out + (size_t)t * N_, amax + (size_t)t * B_);
        k_attn1m<<<dim3(8, B_), 256, 0, stream>>>(amax + (size_t)t * B_, emb, dense_W, dense_b,
                                                  enc, pad, d_out, t, nidbuf, lmask, part);
        k_attn2read<<<dim3(4, B_), 256, 0, stream>>>(part, sent, nidbuf, emb, read_W, read_b, x, mqg);
        float* tmp = (float*)hin; hin = hout; hout = tmp;
    }
    // drain ksim for the final step
    k_ksim<<<dim3(16, B_), 256, 0, stream>>>(mqg, mem_k, normk, key_run);

    k_keyfinal<<<128, 256, 0, stream>>>(key_run, kmask, d_out);
    k_val<<<128, 256, 0, stream>>>(rowmax, mem_k, mem_v, normk, normv, key_run, val_sim);
    k_valout<<<128, 256, 0, stream>>>(val_sim, vmask, d_out);
}

// Round 15
// 2657.924 us; speedup vs baseline: 1.0507x; 1.0507x over previous
//
#include <hip/hip_runtime.h>
#include <cstdint>
#include <cstddef>

#define B_   32
#define SE_  256
#define HE_  512
#define HD_  1024
#define ED_  256
#define N_   8192
#define T_   20
#define KE_  1024
#define VE_  1024
#define MD_  256
#define EIN_ 768
#define NEG_   (-10000000.0f)
#define MAXV_  (1000000000.0f)
#define EPS_   (1e-8f)
#define SPARSE_ 0.8f
#define GATE_  0.78f   // bf16-safe gate; pass-2 recomputes exact f32, false positives harmless

// output offsets (floats)
#define O_IDS  (B_*T_*N_)            // 5242880
#define O_KEY  (O_IDS + B_*T_)       // 5243520
#define O_VAL  (O_KEY + B_*KE_)      // 5276288

typedef __attribute__((ext_vector_type(8))) short short8;
typedef __attribute__((ext_vector_type(4))) float floatx4;

__device__ __forceinline__ float sigf(float v) { return 1.0f / (1.0f + expf(-v)); }

__device__ __forceinline__ short f2bf(float f) {
    union { float f; unsigned u; } v; v.f = f;
    unsigned r = v.u + 0x7FFFu + ((v.u >> 16) & 1u);   // RNE
    return (short)(r >> 16);
}
__device__ __forceinline__ short8 pack8(const float4 a, const float4 b) {
    short8 r;
    r[0]=f2bf(a.x); r[1]=f2bf(a.y); r[2]=f2bf(a.z); r[3]=f2bf(a.w);
    r[4]=f2bf(b.x); r[5]=f2bf(b.y); r[6]=f2bf(b.z); r[7]=f2bf(b.w);
    return r;
}

// ordered-float mapping: monotone uint, handles negatives (no NaN expected)
__device__ __forceinline__ unsigned ord_f(float f) {
    unsigned u = __float_as_uint(f);
    return (u & 0x80000000u) ? ~u : (u | 0x80000000u);
}

// Bool-mask layout probe (verified in an earlier session): int32 vs packed byte.
__device__ __forceinline__ bool mask_is_b8(const void* p) {
    unsigned u = *(const unsigned*)p;
    return u > 0xFFu;
}
__device__ __forceinline__ bool mask_at(const void* p, int idx, bool b8) {
    return b8 ? (((const unsigned char*)p)[idx] != 0)
              : (((const int*)p)[idx] != 0);
}

// ---------------------------------------------------------------- init
__global__ __launch_bounds__(256) void k_init(
    const float* __restrict__ hidden, const float* __restrict__ cell,
    const float* __restrict__ enc, const void* __restrict__ encmask,
    float* __restrict__ h, float* __restrict__ c, float* __restrict__ x,
    float* __restrict__ lmask, float* __restrict__ sent, float* __restrict__ pad,
    float* __restrict__ key_run, float* __restrict__ val_sim, float* __restrict__ rowmax,
    unsigned long long* __restrict__ amax)
{
    int idx = blockIdx.x * 256 + threadIdx.x;   // 0 .. 262143
    lmask[idx] = 0.0f;
    if (idx < T_ * B_) amax[idx] = 0ULL;        // packed argmax slots (ordered 0 = most-negative float)
    if (idx < B_ * HD_) {
        int b = idx >> 10, j = idx & 1023;
        int d = j >> 9, e = j & 511;
        h[idx] = hidden[((size_t)d * B_ + b) * HE_ + e];
        c[idx] = cell  [((size_t)d * B_ + b) * HE_ + e];
        key_run[idx] = -1e30f;
        val_sim[idx] = 0.0f;
        rowmax[idx] = 0.0f;                    // atomicMax target (non-negative)
    }
    if (idx < B_ * EIN_) x[idx] = 0.0f;
    if (idx < B_ * HE_) {
        int b = idx >> 9, e = idx & 511;
        sent[idx] = enc[(size_t)b * SE_ * HE_ + e];
    }
    if (idx < B_ * SE_) {
        bool b8 = mask_is_b8(encmask);
        pad[idx] = mask_at(encmask, idx, b8) ? 0.0f : -MAXV_;
    }
}

// ---------------------------------------------------------------- row norms
__global__ __launch_bounds__(256) void k_norms(
    const float* __restrict__ mem_k, const float* __restrict__ mem_v,
    float* __restrict__ normk, float* __restrict__ normv)
{
    int lane = threadIdx.x & 63;
    int wave = (blockIdx.x * 256 + threadIdx.x) >> 6;   // 0..1023
    for (int row = wave; row < 2 * B_ * KE_; row += 1024) {
        const float* base = (row < B_ * KE_) ? (mem_k + (size_t)row * MD_)
                                             : (mem_v + (size_t)(row - B_ * KE_) * MD_);
        float4 v = ((const float4*)base)[lane];
        float s = v.x*v.x + v.y*v.y + v.z*v.z + v.w*v.w;
        for (int m = 32; m; m >>= 1) s += __shfl_xor(s, m, 64);
        if (lane == 0) {
            if (row < B_ * KE_) normk[row] = sqrtf(s);
            else                normv[row - B_ * KE_] = sqrtf(s);
        }
    }
}

// ---------------------------------------------------------------- rowmax via bf16 MFMA
__global__ __launch_bounds__(256) void k_rowmax_mfma(
    const float* __restrict__ mem_k, const float* __restrict__ mem_v,
    const float* __restrict__ normk, const float* __restrict__ normv,
    float* __restrict__ rowmax)
{
    __shared__ __align__(16) short Vs[64 * 256];   // 32768 B, swizzled
    const int tid = threadIdx.x, lane = tid & 63, w = tid >> 6;
    const int kt = blockIdx.x, vseg = blockIdx.y, b = blockIdx.z;
    const int rowbase = kt * 128 + w * 32;
    const int lrow = lane & 15, lq = lane >> 4;   // lq in 0..3

    float nk[2][4];
    #pragma unroll
    for (int rg = 0; rg < 2; ++rg)
        #pragma unroll
        for (int reg = 0; reg < 4; ++reg)
            nk[rg][reg] = normk[b * KE_ + rowbase + rg * 16 + lq * 4 + reg];

    short8 af[2][8];
    #pragma unroll
    for (int rg = 0; rg < 2; ++rg) {
        const float* arow = mem_k + ((size_t)(b * KE_ + rowbase + rg * 16 + lrow)) * MD_;
        #pragma unroll
        for (int kc = 0; kc < 8; ++kc) {
            const float* p = arow + kc * 32 + lq * 8;
            float4 f0 = *(const float4*)p;
            float4 f1 = *(const float4*)(p + 4);
            af[rg][kc] = pack8(f0, f1);
        }
    }

    float rmax[2][4];
    #pragma unroll
    for (int rg = 0; rg < 2; ++rg)
        #pragma unroll
        for (int reg = 0; reg < 4; ++reg) rmax[rg][reg] = -1e30f;

    for (int vs = vseg * 4; vs < vseg * 4 + 4; ++vs) {
        __syncthreads();
        #pragma unroll
        for (int i = 0; i < 8; ++i) {
            int lin = tid + i * 256;             // 0..2047 = 64 rows x 32 groups
            int r = lin >> 5, cg = lin & 31;
            const float* p = mem_v + ((size_t)(b * VE_ + vs * 64 + r)) * MD_ + cg * 8;
            float4 f0 = *(const float4*)p;
            float4 f1 = *(const float4*)(p + 4);
            int byt = (r * 512 + cg * 16) ^ ((r & 7) << 4);
            *(short8*)((char*)Vs + byt) = pack8(f0, f1);
        }
        __syncthreads();

        for (int vsub = 0; vsub < 4; ++vsub) {
            int vrow = vsub * 16 + lrow;
            float nv = normv[b * VE_ + vs * 64 + vrow];
            short8 bfr[8];
            #pragma unroll
            for (int kc = 0; kc < 8; ++kc) {
                int byt = (vrow * 512 + kc * 64 + lq * 16) ^ ((vrow & 7) << 4);
                bfr[kc] = *(const short8*)((char*)Vs + byt);
            }
            #pragma unroll
            for (int rg = 0; rg < 2; ++rg) {
                floatx4 acc = {0.0f, 0.0f, 0.0f, 0.0f};
                #pragma unroll
                for (int kc = 0; kc < 8; ++kc)
                    acc = __builtin_amdgcn_mfma_f32_16x16x32_bf16(af[rg][kc], bfr[kc], acc, 0, 0, 0);
                #pragma unroll
                for (int reg = 0; reg < 4; ++reg) {
                    float cs = acc[reg] / fmaxf(nk[rg][reg] * nv, EPS_);
                    rmax[rg][reg] = fmaxf(rmax[rg][reg], cs);
                }
            }
        }
    }
    #pragma unroll
    for (int rg = 0; rg < 2; ++rg)
        #pragma unroll
        for (int reg = 0; reg < 4; ++reg) {
            float v = rmax[rg][reg];
            v = fmaxf(v, __shfl_xor(v, 1, 64));
            v = fmaxf(v, __shfl_xor(v, 2, 64));
            v = fmaxf(v, __shfl_xor(v, 4, 64));
            v = fmaxf(v, __shfl_xor(v, 8, 64));
            if (lrow == 0) {
                int* p = (int*)&rowmax[(size_t)b * KE_ + rowbase + rg * 16 + lq * 4 + reg];
                atomicMax(p, __float_as_int(fmaxf(v, 0.0f)));   // non-neg: int order == float order
            }
        }
}

// ---------------------------------------------------------------- wave dot helper (global row x LDS vec)
__device__ __forceinline__ float wave_dot(const float* __restrict__ row, const float* vl, int quads)
{
    int lane = threadIdx.x & 63;
    float s = 0.0f;
    for (int q = lane; q < quads; q += 64) {
        float4 a = ((const float4*)row)[q];
        float4 x = ((const float4*)vl)[q];
        s = fmaf(a.x, x.x, s); s = fmaf(a.y, x.y, s);
        s = fmaf(a.z, x.z, s); s = fmaf(a.w, x.w, s);
    }
    for (int m = 32; m; m >>= 1) s += __shfl_xor(s, m, 64);
    return s;
}

// ---------------------------------------------------------------- COMBINED: gates_t GEMM+LSTM (blocks 0-511) || ksim_{t-1} (blocks 512-1023)
__global__ __launch_bounds__(256) void k_gates_ksim(
    const float* __restrict__ x, const float* __restrict__ W_ih,
    const float* __restrict__ h_in, const float* __restrict__ W_hh,
    const float* __restrict__ b_ih, const float* __restrict__ b_hh,
    float* __restrict__ c_st, float* __restrict__ h_out,
    const float* __restrict__ mqg, const float* __restrict__ mem_k,
    const float* __restrict__ normk, float* __restrict__ key_run, int do_ksim)
{
    __shared__ __align__(16) float Xs[32 * 256];
    __shared__ float red[8][32][17];               // gates role; ksim role aliases Xs
    const int tid = threadIdx.x;

    if (blockIdx.x >= 512) {
        // ======== ksim role (identical math to k_ksim) ========
        if (!do_ksim) return;
        float* mql  = Xs;                          // 256
        float* red2 = Xs + 256;                    // 256
        const int u = blockIdx.x - 512;
        const int kt = u & 15, b = u >> 4;
        const int lane = tid & 63, w = tid >> 6;
        float mv = mqg[(size_t)b * MD_ + tid];
        mql[tid] = mv;
        red2[tid] = mv * mv;
        __syncthreads();
        for (int s = 128; s > 0; s >>= 1) { if (tid < s) red2[tid] += red2[tid + s]; __syncthreads(); }
        float nmq = sqrtf(red2[0]);
        int base = kt * 64 + w * 16;
        for (int i = 0; i < 16; ++i) {
            int k = base + i;
            float num = wave_dot(mem_k + ((size_t)b * KE_ + k) * MD_, mql, MD_ / 4);
            if (lane == 0) {
                float cs = num / fmaxf(nmq * normk[b * KE_ + k], EPS_);
                float o = key_run[b * KE_ + k];
                key_run[b * KE_ + k] = fmaxf(o, cs);
            }
        }
        return;
    }

    // ======== gates role ========
    const int kg = tid & 15, jg = (tid >> 4) & 3, bg = tid >> 6;
    const int ch0 = blockIdx.x * 2;                // 2 channels per block

    float acc[2][8];
    #pragma unroll
    for (int jv = 0; jv < 2; ++jv)
        #pragma unroll
        for (int bv = 0; bv < 8; ++bv) acc[jv][bv] = 0.0f;

    for (int k0 = 0; k0 < EIN_ + HD_; k0 += 256) {
        const bool second = (k0 >= EIN_);
        const float* Xsrc = second ? h_in : x;
        const float* Wsrc = second ? W_hh : W_ih;
        const int srcK = second ? HD_ : EIN_;
        const int ks = second ? (k0 - EIN_) : k0;
        __syncthreads();
        #pragma unroll
        for (int i = 0; i < 8; ++i) {
            int lin = tid + i * 256;
            int bb = lin >> 6, q = lin & 63;
            *(float4*)&Xs[bb * 256 + q * 4] = *(const float4*)(Xsrc + (size_t)bb * srcK + ks + q * 4);
        }
        __syncthreads();
        #pragma unroll
        for (int qq = 0; qq < 4; ++qq) {
            const int qc = kg + qq * 16;
            float4 wv[2];
            #pragma unroll
            for (int jv = 0; jv < 2; ++jv) {
                int row = jg * HD_ + ch0 + jv;     // jg = gate, jv = channel
                wv[jv] = *(const float4*)(Wsrc + (size_t)row * srcK + ks + qc * 4);
            }
            #pragma unroll
            for (int bv = 0; bv < 8; ++bv) {
                float4 x4 = *(const float4*)&Xs[(bg * 8 + bv) * 256 + qc * 4];
                #pragma unroll
                for (int jv = 0; jv < 2; ++jv) {
                    acc[jv][bv] = fmaf(wv[jv].x, x4.x, acc[jv][bv]);
                    acc[jv][bv] = fmaf(wv[jv].y, x4.y, acc[jv][bv]);
                    acc[jv][bv] = fmaf(wv[jv].z, x4.z, acc[jv][bv]);
                    acc[jv][bv] = fmaf(wv[jv].w, x4.w, acc[jv][bv]);
                }
            }
        }
    }
    #pragma unroll
    for (int jv = 0; jv < 2; ++jv)
        #pragma unroll
        for (int bv = 0; bv < 8; ++bv)
            red[jg * 2 + jv][bg * 8 + bv][kg] = acc[jv][bv];
    __syncthreads();
    if (tid < 64) {                                // 2 ch x 32 b
        const int c2 = tid >> 5, b = tid & 31;
        float g4[4];
        #pragma unroll
        for (int gate = 0; gate < 4; ++gate) {
            float s = 0.0f;
            #pragma unroll
            for (int k = 0; k < 16; ++k) s += red[gate * 2 + c2][b][k];
            int row = gate * HD_ + ch0 + c2;
            g4[gate] = s + b_ih[row] + b_hh[row];
        }
        int idx = b * HD_ + ch0 + c2;
        float c1 = sigf(g4[1]) * c_st[idx] + sigf(g4[0]) * tanhf(g4[2]);
        h_out[idx] = sigf(g4[3]) * tanhf(c1);
        c_st[idx] = c1;
    }
}

// ---------------------------------------------------------------- mlp1 relu (256 blocks x 4 j)
__global__ __launch_bounds__(256) void k_mlp1(
    const float* __restrict__ X, const float* __restrict__ W,
    const float* __restrict__ bias, float* __restrict__ out)
{
    __shared__ __align__(16) float Xs[32 * 256];
    __shared__ float red[4][32][17];               // 8.7 KB
    const int tid = threadIdx.x;
    const int kg = tid & 15, jg = (tid >> 4) & 3, bg = tid >> 6;
    const int jbase = blockIdx.x * 4;

    float acc[8];
    #pragma unroll
    for (int bv = 0; bv < 8; ++bv) acc[bv] = 0.0f;

    for (int k0 = 0; k0 < HD_; k0 += 256) {
        __syncthreads();
        #pragma unroll
        for (int i = 0; i < 8; ++i) {
            int lin = tid + i * 256;
            int bb = lin >> 6, q = lin & 63;
            *(float4*)&Xs[bb * 256 + q * 4] = *(const float4*)(X + (size_t)bb * HD_ + k0 + q * 4);
        }
        __syncthreads();
        #pragma unroll
        for (int qq = 0; qq < 4; ++qq) {
            const int qc = kg + qq * 16;
            float4 w4 = *(const float4*)(W + (size_t)(jbase + jg) * HD_ + k0 + qc * 4);
            #pragma unroll
            for (int bv = 0; bv < 8; ++bv) {
                float4 x4 = *(const float4*)&Xs[(bg * 8 + bv) * 256 + qc * 4];
                acc[bv] = fmaf(w4.x, x4.x, acc[bv]);
                acc[bv] = fmaf(w4.y, x4.y, acc[bv]);
                acc[bv] = fmaf(w4.z, x4.z, acc[bv]);
                acc[bv] = fmaf(w4.w, x4.w, acc[bv]);
            }
        }
    }
    #pragma unroll
    for (int bv = 0; bv < 8; ++bv)
        red[jg][bg * 8 + bv][kg] = acc[bv];
    __syncthreads();
    if (tid < 128) {                               // 4 j x 32 b
        int jjo = tid >> 5, b = tid & 31;
        float s = 0.0f;
        #pragma unroll
        for (int k = 0; k < 16; ++k) s += red[jjo][b][k];
        int jo = jbase + jjo;
        out[(size_t)b * HD_ + jo] = fmaxf(s + bias[jo], 0.0f);
    }
}

// ---------------------------------------------------------------- logits GEMM + lmask + packed-atomic argmax
// (atomic argmax verified correct in round 10; replaces pval/pidx scan)
__global__ __launch_bounds__(256) void k_logits(
    const float* __restrict__ hid, const float* __restrict__ W2,
    const float* __restrict__ b2, const float* __restrict__ lmask,
    float* __restrict__ lg_out, unsigned long long* __restrict__ amax_t)
{
    __shared__ __align__(16) float Xs[32 * 256];
    __shared__ float red[16][32][17];
    const int tid = threadIdx.x;
    const int kg = tid & 15, jg = (tid >> 4) & 3, bg = tid >> 6;
    const int jbase = blockIdx.x * 16;

    float acc[4][8];
    #pragma unroll
    for (int jv = 0; jv < 4; ++jv)
        #pragma unroll
        for (int bv = 0; bv < 8; ++bv) acc[jv][bv] = 0.0f;

    for (int k0 = 0; k0 < HD_; k0 += 256) {
        __syncthreads();
        #pragma unroll
        for (int i = 0; i < 8; ++i) {
            int lin = tid + i * 256;
            int bb = lin >> 6, q = lin & 63;
            *(float4*)&Xs[bb * 256 + q * 4] = *(const float4*)(hid + (size_t)bb * HD_ + k0 + q * 4);
        }
        __syncthreads();
        #pragma unroll
        for (int qq = 0; qq < 4; ++qq) {
            const int qc = kg + qq * 16;
            float4 wv[4];
            #pragma unroll
            for (int jv = 0; jv < 4; ++jv)
                wv[jv] = *(const float4*)(W2 + (size_t)(jbase + jg * 4 + jv) * HD_ + k0 + qc * 4);
            #pragma unroll
            for (int bv = 0; bv < 8; ++bv) {
                float4 x4 = *(const float4*)&Xs[(bg * 8 + bv) * 256 + qc * 4];
                #pragma unroll
                for (int jv = 0; jv < 4; ++jv) {
                    acc[jv][bv] = fmaf(wv[jv].x, x4.x, acc[jv][bv]);
                    acc[jv][bv] = fmaf(wv[jv].y, x4.y, acc[jv][bv]);
                    acc[jv][bv] = fmaf(wv[jv].z, x4.z, acc[jv][bv]);
                    acc[jv][bv] = fmaf(wv[jv].w, x4.w, acc[jv][bv]);
                }
            }
        }
    }
    #pragma unroll
    for (int jv = 0; jv < 4; ++jv)
        #pragma unroll
        for (int bv = 0; bv < 8; ++bv)
            red[jg * 4 + jv][bg * 8 + bv][kg] = acc[jv][bv];
    __syncthreads();
    for (int o = tid; o < 16 * B_; o += 256) {
        int jjo = o >> 5, b = o & 31;
        float s = 0.0f;
        #pragma unroll
        for (int k = 0; k < 16; ++k) s += red[jjo][b][k];
        int jo = jbase + jjo;
        s += b2[jo] + lmask[(size_t)b * N_ + jo];
        lg_out[(size_t)b * (T_ * N_) + jo] = s;
        red[jjo][b][16] = s;
    }
    __syncthreads();
    if (tid < 32) {
        int b = tid;
        float best = -1e38f; int bi = 0;
        #pragma unroll
        for (int jjo = 0; jjo < 16; ++jjo) {
            float v = red[jjo][b][16];
            if (v > best) { best = v; bi = jjo; }   // strict > keeps smallest j within block
        }
        // pack: ordered(value) in high 32, (N-1-idx) in low 32 — ties resolve to smallest idx
        unsigned long long packed =
            ((unsigned long long)ord_f(best) << 32) | (unsigned)(N_ - 1 - (jbase + bi));
        atomicMax(&amax_t[b], packed);
    }
}

// ---------------------------------------------------------------- slim merge: decode argmax slot + lmask + q = emb[nid]@dense_W^T
__global__ __launch_bounds__(256) void k_merge(
    const unsigned long long* __restrict__ amax_t,
    float* __restrict__ d_out, int t, int* __restrict__ nidbuf,
    float* __restrict__ lmask, const float* __restrict__ emb,
    const float* __restrict__ dense_W, const float* __restrict__ dense_b,
    float* __restrict__ qbuf)
{
    __shared__ __align__(16) float lab[ED_];
    const int b = blockIdx.x, tid = threadIdx.x;
    const int nid = N_ - 1 - (int)(amax_t[b] & 0xFFFFFFFFULL);
    if (tid == 0) {
        nidbuf[b] = nid;
        d_out[O_IDS + (size_t)b * T_ + t] = (float)nid;
        lmask[(size_t)b * N_ + nid] = NEG_;
        lmask[(size_t)b * N_] = 0.0f;             // EOS unmask (covers nid==0 too)
    }
    lab[tid] = emb[(size_t)nid * ED_ + tid];
    __syncthreads();
    const float4* Lq = (const float4*)lab;
    #pragma unroll
    for (int jj = 0; jj < 2; ++jj) {
        int j = tid + jj * 256;
        const float4* Wq = (const float4*)(dense_W + (size_t)j * ED_);
        float s0 = 0.0f, s1 = 0.0f, s2 = 0.0f, s3 = 0.0f;
        #pragma unroll
        for (int q = 0; q < 64; q += 4) {
            float4 w0 = Wq[q],   x0 = Lq[q];
            float4 w1 = Wq[q+1], x1 = Lq[q+1];
            float4 w2 = Wq[q+2], x2 = Lq[q+2];
            float4 w3 = Wq[q+3], x3 = Lq[q+3];
            s0 = fmaf(w0.x,x0.x,s0); s0 = fmaf(w0.y,x0.y,s0); s0 = fmaf(w0.z,x0.z,s0); s0 = fmaf(w0.w,x0.w,s0);
            s1 = fmaf(w1.x,x1.x,s1); s1 = fmaf(w1.y,x1.y,s1); s1 = fmaf(w1.z,x1.z,s1); s1 = fmaf(w1.w,x1.w,s1);
            s2 = fmaf(w2.x,x2.x,s2); s2 = fmaf(w2.y,x2.y,s2); s2 = fmaf(w2.z,x2.z,s2); s2 = fmaf(w2.w,x2.w,s2);
            s3 = fmaf(w3.x,x3.x,s3); s3 = fmaf(w3.y,x3.y,s3); s3 = fmaf(w3.z,x3.z,s3); s3 = fmaf(w3.w,x3.w,s3);
        }
        qbuf[(size_t)b * HE_ + j] = dense_b[j] + ((s0 + s1) + (s2 + s3));
    }
}

// ---------------------------------------------------------------- attn pass 1: per 32-s chunk scores + online-softmax partials
__global__ __launch_bounds__(256) void k_attn1(
    const float* __restrict__ qg, const float* __restrict__ enc,
    const float* __restrict__ pad, float* __restrict__ part)
{
    __shared__ __align__(16) float ql[HE_];
    __shared__ float sc_l[32];
    __shared__ float wp_l[32];
    const int b = blockIdx.y, sc = blockIdx.x;
    const int tid = threadIdx.x, lane = tid & 63, w = tid >> 6;
    ql[tid] = qg[(size_t)b * HE_ + tid];
    ql[tid + 256] = qg[(size_t)b * HE_ + tid + 256];
    __syncthreads();

    #pragma unroll
    for (int i = 0; i < 8; ++i) {
        int sl = w + i * 4;
        int s = sc * 32 + sl;
        float v = wave_dot(enc + ((size_t)b * SE_ + s) * HE_, ql, HE_ / 4);
        if (lane == 0) sc_l[sl] = v + pad[b * SE_ + s];
    }
    __syncthreads();

    float m = -1e38f;
    #pragma unroll
    for (int i = 0; i < 32; ++i) m = fmaxf(m, sc_l[i]);
    if (tid < 32) wp_l[tid] = expf(sc_l[tid] - m);
    __syncthreads();
    float esum = 0.0f;
    #pragma unroll
    for (int i = 0; i < 32; ++i) esum += wp_l[i];

    float a0 = 0.0f, a1 = 0.0f;
    for (int i = 0; i < 32; ++i) {
        float wv = wp_l[i];
        const float* er = enc + ((size_t)b * SE_ + sc * 32 + i) * HE_;
        a0 = fmaf(wv, er[tid], a0);
        a1 = fmaf(wv, er[tid + 256], a1);
    }
    float* pb = part + ((size_t)b * 8 + sc) * 516;
    pb[tid] = a0;
    pb[256 + tid] = a1;
    if (tid == 0) { pb[512] = m; pb[513] = esum; }
}

// ---------------------------------------------------------------- attn pass 2 + x build + mq = x@read_W^T (grid 4 x 32)
__global__ __launch_bounds__(256) void k_attn2read(
    const float* __restrict__ part, const float* __restrict__ sent,
    const int* __restrict__ nidbuf, const float* __restrict__ emb,
    const float* __restrict__ read_W, const float* __restrict__ read_b,
    float* __restrict__ xg, float* __restrict__ mqg)
{
    __shared__ float ms[8], es[8];
    __shared__ __align__(16) float xl[EIN_];
    const int qv = blockIdx.x, b = blockIdx.y;
    const int tid = threadIdx.x;
    if (tid < 8) {
        ms[tid] = part[((size_t)b * 8 + tid) * 516 + 512];
        es[tid] = part[((size_t)b * 8 + tid) * 516 + 513];
    }
    __syncthreads();
    float m = -1e38f;
    #pragma unroll
    for (int c = 0; c < 8; ++c) m = fmaxf(m, ms[c]);
    float scale[8];
    float denom = 0.0f;
    #pragma unroll
    for (int c = 0; c < 8; ++c) { scale[c] = expf(ms[c] - m); denom += es[c] * scale[c]; }
    float inv = 1.0f / denom;
    float a0 = 0.0f, a1 = 0.0f;
    #pragma unroll
    for (int c = 0; c < 8; ++c) {
        const float* pb = part + ((size_t)b * 8 + c) * 516;
        a0 = fmaf(scale[c], pb[tid], a0);
        a1 = fmaf(scale[c], pb[256 + tid], a1);
    }
    a0 *= inv; a1 *= inv;
    int nid = nidbuf[b];
    xl[tid]             = emb[(size_t)nid * ED_ + tid];
    xl[ED_ + tid]       = sent[(size_t)b * HE_ + tid]       + a0;
    xl[ED_ + 256 + tid] = sent[(size_t)b * HE_ + 256 + tid] + a1;
    __syncthreads();
    if (qv == 0) {
        float* xr = xg + (size_t)b * EIN_;
        xr[tid] = xl[tid]; xr[tid + 256] = xl[tid + 256]; xr[tid + 512] = xl[tid + 512];
    }
    // mq rows [qv*64, qv*64+64): 4 threads per row, quarter-K each
    const int r = qv * 64 + (tid >> 2), kq = tid & 3;
    const float4* Wq = (const float4*)(read_W + (size_t)r * EIN_ + kq * 192);
    const float4* xq = (const float4*)(xl + kq * 192);
    float s0 = 0.0f, s1 = 0.0f, s2 = 0.0f, s3 = 0.0f;
    #pragma unroll
    for (int q = 0; q < 48; q += 4) {
        float4 w0 = Wq[q],   v0 = xq[q];
        float4 w1 = Wq[q+1], v1 = xq[q+1];
        float4 w2 = Wq[q+2], v2 = xq[q+2];
        float4 w3 = Wq[q+3], v3 = xq[q+3];
        s0 = fmaf(w0.x,v0.x,s0); s0 = fmaf(w0.y,v0.y,s0); s0 = fmaf(w0.z,v0.z,s0); s0 = fmaf(w0.w,v0.w,s0);
        s1 = fmaf(w1.x,v1.x,s1); s1 = fmaf(w1.y,v1.y,s1); s1 = fmaf(w1.z,v1.z,s1); s1 = fmaf(w1.w,v1.w,s1);
        s2 = fmaf(w2.x,v2.x,s2); s2 = fmaf(w2.y,v2.y,s2); s2 = fmaf(w2.z,v2.z,s2); s2 = fmaf(w2.w,v2.w,s2);
        s3 = fmaf(w3.x,v3.x,s3); s3 = fmaf(w3.z,v3.z,s3); s3 = fmaf(w3.y,v3.y,s3); s3 = fmaf(w3.w,v3.w,s3);
    }
    float s = ((s0 + s1) + (s2 + s3));
    s += __shfl_xor(s, 1, 64);
    s += __shfl_xor(s, 2, 64);
    if (kq == 0) mqg[(size_t)b * MD_ + r] = s + read_b[r];
}

// ---------------------------------------------------------------- ksim standalone (final step drain) — grid (16 kt, 32 b)
__global__ __launch_bounds__(256) void k_ksim(
    const float* __restrict__ mqg,
    const float* __restrict__ mem_k, const float* __restrict__ normk,
    float* __restrict__ key_run)
{
    __shared__ __align__(16) float mql[MD_];
    __shared__ float red[256];
    const int b = blockIdx.y, kt = blockIdx.x;    // kt 0..15
    const int tid = threadIdx.x, lane = tid & 63, w = tid >> 6;
    float mv = mqg[(size_t)b * MD_ + tid];
    mql[tid] = mv;
    red[tid] = mv * mv;
    __syncthreads();
    for (int s = 128; s > 0; s >>= 1) { if (tid < s) red[tid] += red[tid + s]; __syncthreads(); }
    float nmq = sqrtf(red[0]);

    int base = kt * 64 + w * 16;
    for (int i = 0; i < 16; ++i) {
        int k = base + i;
        float num = wave_dot(mem_k + ((size_t)b * KE_ + k) * MD_, mql, MD_ / 4);
        if (lane == 0) {
            float cs = num / fmaxf(nmq * normk[b * KE_ + k], EPS_);
            float o = key_run[b * KE_ + k];
            key_run[b * KE_ + k] = fmaxf(o, cs);
        }
    }
}

// ---------------------------------------------------------------- key finalize + key_out
__global__ __launch_bounds__(256) void k_keyfinal(
    float* __restrict__ key_run, const void* __restrict__ kmask, float* __restrict__ d_out)
{
    int idx = blockIdx.x * 256 + threadIdx.x;    // 0..32767
    bool b8 = mask_is_b8(kmask);
    float v = key_run[idx];
    v = (v < 0.0f) ? 0.0f : v;
    key_run[idx] = v;
    d_out[O_KEY + idx] = mask_at(kmask, idx, b8) ? v : -1.0f;
}

// ---------------------------------------------------------------- val contributions (rows gated by bf16 rowmax; exact f32 recompute)
__global__ __launch_bounds__(256) void k_val(
    const float* __restrict__ rowmax, const float* __restrict__ mem_k, const float* __restrict__ mem_v,
    const float* __restrict__ normk, const float* __restrict__ normv,
    const float* __restrict__ key_sim, float* __restrict__ val_sim)
{
    int idx = blockIdx.x * 256 + threadIdx.x;    // 0..32767 : (b,k)
    if (rowmax[idx] < GATE_) return;
    int b = idx >> 10;
    const float* krow = mem_k + (size_t)idx * MD_;
    float nk = normk[idx];
    float ks = key_sim[idx];
    float rm = -1e30f;
    for (int v = 0; v < VE_; ++v) {
        const float* vrow = mem_v + ((size_t)b * VE_ + v) * MD_;
        float d = 0.0f;
        for (int e = 0; e < MD_; ++e) d = fmaf(krow[e], vrow[e], d);
        float cs = d / fmaxf(nk * normv[b * VE_ + v], EPS_);
        rm = fmaxf(rm, cs);
    }
    float thr = fmaxf(rm, SPARSE_);
    for (int v = 0; v < VE_; ++v) {
        const float* vrow = mem_v + ((size_t)b * VE_ + v) * MD_;
        float d = 0.0f;
        for (int e = 0; e < MD_; ++e) d = fmaf(krow[e], vrow[e], d);
        float cs = d / fmaxf(nk * normv[b * VE_ + v], EPS_);
        if (cs >= thr) atomicAdd(&val_sim[(size_t)b * VE_ + v], ks * cs);
    }
}

// ---------------------------------------------------------------- val_out
__global__ __launch_bounds__(256) void k_valout(
    const float* __restrict__ val_sim, const void* __restrict__ vmask, float* __restrict__ d_out)
{
    int idx = blockIdx.x * 256 + threadIdx.x;
    bool b8 = mask_is_b8(vmask);
    d_out[O_VAL + idx] = mask_at(vmask, idx, b8) ? val_sim[idx] : -1.0f;
}

// ================================================================ launch
extern "C" void kernel_launch(void* const* d_in, const int* in_sizes, int n_in,
                              void* d_out_v, int out_size, void* d_ws, size_t ws_size,
                              hipStream_t stream)
{
    const float* enc      = (const float*)d_in[0];
    const float* hidden   = (const float*)d_in[1];
    const float* cell     = (const float*)d_in[2];
    const void*  encmask  = d_in[4];
    const void*  kmask    = d_in[5];
    const float* mem_k    = (const float*)d_in[6];
    const void*  vmask    = d_in[7];
    const float* mem_v    = (const float*)d_in[8];
    const float* W_ih     = (const float*)d_in[9];
    const float* W_hh     = (const float*)d_in[10];
    const float* b_ih     = (const float*)d_in[11];
    const float* b_hh     = (const float*)d_in[12];
    const float* mlp_W1   = (const float*)d_in[13];
    const float* mlp_b1   = (const float*)d_in[14];
    const float* mlp_W2   = (const float*)d_in[15];
    const float* mlp_b2   = (const float*)d_in[16];
    const float* emb      = (const float*)d_in[17];
    const float* dense_W  = (const float*)d_in[18];
    const float* dense_b  = (const float*)d_in[19];
    const float* read_W   = (const float*)d_in[20];
    const float* read_b   = (const float*)d_in[21];
    float* d_out = (float*)d_out_v;
    float* ws = (float*)d_ws;

    float* hA      = ws;             // 32768
    float* hB      = ws + 32768;     // 32768
    float* c       = ws + 65536;     // 32768
    float* x       = ws + 98304;     // 24576
    float* hid     = ws + 122880;    // 32768
    float* lmask   = ws + 155648;    // 262144
    float* sent    = ws + 417792;    // 16384
    float* pad     = ws + 434176;    // 8192
    float* key_run = ws + 442368;    // 32768
    float* val_sim = ws + 475136;    // 32768
    float* normk   = ws + 507904;    // 32768
    float* normv   = ws + 540672;    // 32768
    float* rowmax  = ws + 573440;    // 32768
    int*   nidbuf  = (int*)(ws + 606208); // 64
    float* mqg     = ws + 606272;    // 8192
    float* qbuf    = ws + 614464;    // 16384
    float* part    = ws + 630848;    // 132096
    unsigned long long* amax = (unsigned long long*)(ws + 762944); // T_*B_=640 slots (5 KB)
    // total ≈ 764224 floats ≈ 2.92 MB

    k_init<<<1024, 256, 0, stream>>>(hidden, cell, enc, encmask, hA, c, x, lmask, sent, pad,
                                     key_run, val_sim, rowmax, amax);
    k_norms<<<256, 256, 0, stream>>>(mem_k, mem_v, normk, normv);
    k_rowmax_mfma<<<dim3(8, 4, 32), 256, 0, stream>>>(mem_k, mem_v, normk, normv, rowmax);

    const float* hin = hA;
    float* hout = hB;
    for (int t = 0; t < T_; ++t) {
        // gates_t co-launched with ksim_{t-1} (independent; both ready after attn2read_{t-1})
        k_gates_ksim<<<1024, 256, 0, stream>>>(x, W_ih, hin, W_hh, b_ih, b_hh, c, hout,
                                               mqg, mem_k, normk, key_run, t > 0 ? 1 : 0);
        k_mlp1<<<HD_ / 4, 256, 0, stream>>>(hout, mlp_W1, mlp_b1, hid);
        k_logits<<<N_ / 16, 256, 0, stream>>>(hid, mlp_W2, mlp_b2, lmask,
                                              d_out + (size_t)t * N_, amax + (size_t)t * B_);
        k_merge<<<B_, 256, 0, stream>>>(amax + (size_t)t * B_, d_out, t, nidbuf, lmask,
                                        emb, dense_W, dense_b, qbuf);
        k_attn1<<<dim3(8, B_), 256, 0, stream>>>(qbuf, enc, pad, part);
        k_attn2read<<<dim3(4, B_), 256, 0, stream>>>(part, sent, nidbuf, emb, read_W, read_b, x, mqg);
        float* tmp = (float*)hin; hin = hout; hout = tmp;
    }
    // drain ksim for the final step
    k_ksim<<<dim3(16, B_), 256, 0, stream>>>(mqg, mem_k, normk, key_run);

    k_keyfinal<<<128, 256, 0, stream>>>(key_run, kmask, d_out);
    k_val<<<128, 256, 0, stream>>>(rowmax, mem_k, mem_v, normk, normv, key_run, val_sim);
    k_valout<<<128, 256, 0, stream>>>(val_sim, vmask, d_out);
}

// Round 16
// 2550.415 us; speedup vs baseline: 1.0950x; 1.0422x over previous
//
#include <hip/hip_runtime.h>
#include <cstdint>
#include <cstddef>

#define B_   32
#define SE_  256
#define HE_  512
#define HD_  1024
#define ED_  256
#define N_   8192
#define T_   20
#define KE_  1024
#define VE_  1024
#define MD_  256
#define EIN_ 768
#define NEG_   (-10000000.0f)
#define MAXV_  (1000000000.0f)
#define EPS_   (1e-8f)
#define SPARSE_ 0.8f
#define GATE_  0.78f   // bf16-safe gate; pass-2 recomputes exact f32, false positives harmless

#define NLOGB (N_/16)  // 512 logits blocks -> partial argmax entries per b

// output offsets (floats)
#define O_IDS  (B_*T_*N_)            // 5242880
#define O_KEY  (O_IDS + B_*T_)       // 5243520
#define O_VAL  (O_KEY + B_*KE_)      // 5276288

typedef __attribute__((ext_vector_type(8))) short short8;
typedef __attribute__((ext_vector_type(4))) float floatx4;

__device__ __forceinline__ float sigf(float v) { return 1.0f / (1.0f + expf(-v)); }

__device__ __forceinline__ short f2bf(float f) {
    union { float f; unsigned u; } v; v.f = f;
    unsigned r = v.u + 0x7FFFu + ((v.u >> 16) & 1u);   // RNE
    return (short)(r >> 16);
}
__device__ __forceinline__ short8 pack8(const float4 a, const float4 b) {
    short8 r;
    r[0]=f2bf(a.x); r[1]=f2bf(a.y); r[2]=f2bf(a.z); r[3]=f2bf(a.w);
    r[4]=f2bf(b.x); r[5]=f2bf(b.y); r[6]=f2bf(b.z); r[7]=f2bf(b.w);
    return r;
}

// Bool-mask layout probe (verified in an earlier session): int32 vs packed byte.
__device__ __forceinline__ bool mask_is_b8(const void* p) {
    unsigned u = *(const unsigned*)p;
    return u > 0xFFu;
}
__device__ __forceinline__ bool mask_at(const void* p, int idx, bool b8) {
    return b8 ? (((const unsigned char*)p)[idx] != 0)
              : (((const int*)p)[idx] != 0);
}

// ---------------------------------------------------------------- init
__global__ __launch_bounds__(256) void k_init(
    const float* __restrict__ hidden, const float* __restrict__ cell,
    const float* __restrict__ enc, const void* __restrict__ encmask,
    float* __restrict__ h, float* __restrict__ c, float* __restrict__ x,
    float* __restrict__ lmask, float* __restrict__ sent, float* __restrict__ pad,
    float* __restrict__ key_run, float* __restrict__ val_sim, float* __restrict__ rowmax)
{
    int idx = blockIdx.x * 256 + threadIdx.x;   // 0 .. 262143
    lmask[idx] = 0.0f;
    if (idx < B_ * HD_) {
        int b = idx >> 10, j = idx & 1023;
        int d = j >> 9, e = j & 511;
        h[idx] = hidden[((size_t)d * B_ + b) * HE_ + e];
        c[idx] = cell  [((size_t)d * B_ + b) * HE_ + e];
        key_run[idx] = -1e30f;
        val_sim[idx] = 0.0f;
        rowmax[idx] = 0.0f;                    // atomicMax target (non-negative)
    }
    if (idx < B_ * EIN_) x[idx] = 0.0f;
    if (idx < B_ * HE_) {
        int b = idx >> 9, e = idx & 511;
        sent[idx] = enc[(size_t)b * SE_ * HE_ + e];
    }
    if (idx < B_ * SE_) {
        bool b8 = mask_is_b8(encmask);
        pad[idx] = mask_at(encmask, idx, b8) ? 0.0f : -MAXV_;
    }
}

// ---------------------------------------------------------------- row norms
__global__ __launch_bounds__(256) void k_norms(
    const float* __restrict__ mem_k, const float* __restrict__ mem_v,
    float* __restrict__ normk, float* __restrict__ normv)
{
    int lane = threadIdx.x & 63;
    int wave = (blockIdx.x * 256 + threadIdx.x) >> 6;   // 0..1023
    for (int row = wave; row < 2 * B_ * KE_; row += 1024) {
        const float* base = (row < B_ * KE_) ? (mem_k + (size_t)row * MD_)
                                             : (mem_v + (size_t)(row - B_ * KE_) * MD_);
        float4 v = ((const float4*)base)[lane];
        float s = v.x*v.x + v.y*v.y + v.z*v.z + v.w*v.w;
        for (int m = 32; m; m >>= 1) s += __shfl_xor(s, m, 64);
        if (lane == 0) {
            if (row < B_ * KE_) normk[row] = sqrtf(s);
            else                normv[row - B_ * KE_] = sqrtf(s);
        }
    }
}

// ---------------------------------------------------------------- rowmax via bf16 MFMA
__global__ __launch_bounds__(256) void k_rowmax_mfma(
    const float* __restrict__ mem_k, const float* __restrict__ mem_v,
    const float* __restrict__ normk, const float* __restrict__ normv,
    float* __restrict__ rowmax)
{
    __shared__ __align__(16) short Vs[64 * 256];   // 32768 B, swizzled
    const int tid = threadIdx.x, lane = tid & 63, w = tid >> 6;
    const int kt = blockIdx.x, vseg = blockIdx.y, b = blockIdx.z;
    const int rowbase = kt * 128 + w * 32;
    const int lrow = lane & 15, lq = lane >> 4;   // lq in 0..3

    float nk[2][4];
    #pragma unroll
    for (int rg = 0; rg < 2; ++rg)
        #pragma unroll
        for (int reg = 0; reg < 4; ++reg)
            nk[rg][reg] = normk[b * KE_ + rowbase + rg * 16 + lq * 4 + reg];

    short8 af[2][8];
    #pragma unroll
    for (int rg = 0; rg < 2; ++rg) {
        const float* arow = mem_k + ((size_t)(b * KE_ + rowbase + rg * 16 + lrow)) * MD_;
        #pragma unroll
        for (int kc = 0; kc < 8; ++kc) {
            const float* p = arow + kc * 32 + lq * 8;
            float4 f0 = *(const float4*)p;
            float4 f1 = *(const float4*)(p + 4);
            af[rg][kc] = pack8(f0, f1);
        }
    }

    float rmax[2][4];
    #pragma unroll
    for (int rg = 0; rg < 2; ++rg)
        #pragma unroll
        for (int reg = 0; reg < 4; ++reg) rmax[rg][reg] = -1e30f;

    for (int vs = vseg * 4; vs < vseg * 4 + 4; ++vs) {
        __syncthreads();
        #pragma unroll
        for (int i = 0; i < 8; ++i) {
            int lin = tid + i * 256;             // 0..2047 = 64 rows x 32 groups
            int r = lin >> 5, cg = lin & 31;
            const float* p = mem_v + ((size_t)(b * VE_ + vs * 64 + r)) * MD_ + cg * 8;
            float4 f0 = *(const float4*)p;
            float4 f1 = *(const float4*)(p + 4);
            int byt = (r * 512 + cg * 16) ^ ((r & 7) << 4);
            *(short8*)((char*)Vs + byt) = pack8(f0, f1);
        }
        __syncthreads();

        for (int vsub = 0; vsub < 4; ++vsub) {
            int vrow = vsub * 16 + lrow;
            float nv = normv[b * VE_ + vs * 64 + vrow];
            short8 bfr[8];
            #pragma unroll
            for (int kc = 0; kc < 8; ++kc) {
                int byt = (vrow * 512 + kc * 64 + lq * 16) ^ ((vrow & 7) << 4);
                bfr[kc] = *(const short8*)((char*)Vs + byt);
            }
            #pragma unroll
            for (int rg = 0; rg < 2; ++rg) {
                floatx4 acc = {0.0f, 0.0f, 0.0f, 0.0f};
                #pragma unroll
                for (int kc = 0; kc < 8; ++kc)
                    acc = __builtin_amdgcn_mfma_f32_16x16x32_bf16(af[rg][kc], bfr[kc], acc, 0, 0, 0);
                #pragma unroll
                for (int reg = 0; reg < 4; ++reg) {
                    float cs = acc[reg] / fmaxf(nk[rg][reg] * nv, EPS_);
                    rmax[rg][reg] = fmaxf(rmax[rg][reg], cs);
                }
            }
        }
    }
    #pragma unroll
    for (int rg = 0; rg < 2; ++rg)
        #pragma unroll
        for (int reg = 0; reg < 4; ++reg) {
            float v = rmax[rg][reg];
            v = fmaxf(v, __shfl_xor(v, 1, 64));
            v = fmaxf(v, __shfl_xor(v, 2, 64));
            v = fmaxf(v, __shfl_xor(v, 4, 64));
            v = fmaxf(v, __shfl_xor(v, 8, 64));
            if (lrow == 0) {
                int* p = (int*)&rowmax[(size_t)b * KE_ + rowbase + rg * 16 + lq * 4 + reg];
                atomicMax(p, __float_as_int(fmaxf(v, 0.0f)));   // non-neg: int order == float order
            }
        }
}

// ---------------------------------------------------------------- wave dot helper (global row x LDS vec)
__device__ __forceinline__ float wave_dot(const float* __restrict__ row, const float* vl, int quads)
{
    int lane = threadIdx.x & 63;
    float s = 0.0f;
    for (int q = lane; q < quads; q += 64) {
        float4 a = ((const float4*)row)[q];
        float4 x = ((const float4*)vl)[q];
        s = fmaf(a.x, x.x, s); s = fmaf(a.y, x.y, s);
        s = fmaf(a.z, x.z, s); s = fmaf(a.w, x.w, s);
    }
    for (int m = 32; m; m >>= 1) s += __shfl_xor(s, m, 64);
    return s;
}

// ---------------------------------------------------------------- COMBINED: gates_t GEMM+LSTM (blocks 0-511) || ksim_{t-1} (blocks 512-1023)
__global__ __launch_bounds__(256) void k_gates_ksim(
    const float* __restrict__ x, const float* __restrict__ W_ih,
    const float* __restrict__ h_in, const float* __restrict__ W_hh,
    const float* __restrict__ b_ih, const float* __restrict__ b_hh,
    float* __restrict__ c_st, float* __restrict__ h_out,
    const float* __restrict__ mqg, const float* __restrict__ mem_k,
    const float* __restrict__ normk, float* __restrict__ key_run, int do_ksim)
{
    __shared__ __align__(16) float Xs[32 * 256];
    __shared__ float red[8][32][17];               // gates role; ksim role aliases Xs
    const int tid = threadIdx.x;

    if (blockIdx.x >= 512) {
        // ======== ksim role (identical math to k_ksim) ========
        if (!do_ksim) return;
        float* mql  = Xs;                          // 256
        float* red2 = Xs + 256;                    // 256
        const int u = blockIdx.x - 512;
        const int kt = u & 15, b = u >> 4;
        const int lane = tid & 63, w = tid >> 6;
        float mv = mqg[(size_t)b * MD_ + tid];
        mql[tid] = mv;
        red2[tid] = mv * mv;
        __syncthreads();
        for (int s = 128; s > 0; s >>= 1) { if (tid < s) red2[tid] += red2[tid + s]; __syncthreads(); }
        float nmq = sqrtf(red2[0]);
        int base = kt * 64 + w * 16;
        for (int i = 0; i < 16; ++i) {
            int k = base + i;
            float num = wave_dot(mem_k + ((size_t)b * KE_ + k) * MD_, mql, MD_ / 4);
            if (lane == 0) {
                float cs = num / fmaxf(nmq * normk[b * KE_ + k], EPS_);
                float o = key_run[b * KE_ + k];
                key_run[b * KE_ + k] = fmaxf(o, cs);
            }
        }
        return;
    }

    // ======== gates role ========
    const int kg = tid & 15, jg = (tid >> 4) & 3, bg = tid >> 6;
    const int ch0 = blockIdx.x * 2;                // 2 channels per block

    float acc[2][8];
    #pragma unroll
    for (int jv = 0; jv < 2; ++jv)
        #pragma unroll
        for (int bv = 0; bv < 8; ++bv) acc[jv][bv] = 0.0f;

    for (int k0 = 0; k0 < EIN_ + HD_; k0 += 256) {
        const bool second = (k0 >= EIN_);
        const float* Xsrc = second ? h_in : x;
        const float* Wsrc = second ? W_hh : W_ih;
        const int srcK = second ? HD_ : EIN_;
        const int ks = second ? (k0 - EIN_) : k0;
        __syncthreads();
        #pragma unroll
        for (int i = 0; i < 8; ++i) {
            int lin = tid + i * 256;
            int bb = lin >> 6, q = lin & 63;
            *(float4*)&Xs[bb * 256 + q * 4] = *(const float4*)(Xsrc + (size_t)bb * srcK + ks + q * 4);
        }
        __syncthreads();
        #pragma unroll
        for (int qq = 0; qq < 4; ++qq) {
            const int qc = kg + qq * 16;
            float4 wv[2];
            #pragma unroll
            for (int jv = 0; jv < 2; ++jv) {
                int row = jg * HD_ + ch0 + jv;     // jg = gate, jv = channel
                wv[jv] = *(const float4*)(Wsrc + (size_t)row * srcK + ks + qc * 4);
            }
            #pragma unroll
            for (int bv = 0; bv < 8; ++bv) {
                float4 x4 = *(const float4*)&Xs[(bg * 8 + bv) * 256 + qc * 4];
                #pragma unroll
                for (int jv = 0; jv < 2; ++jv) {
                    acc[jv][bv] = fmaf(wv[jv].x, x4.x, acc[jv][bv]);
                    acc[jv][bv] = fmaf(wv[jv].y, x4.y, acc[jv][bv]);
                    acc[jv][bv] = fmaf(wv[jv].z, x4.z, acc[jv][bv]);
                    acc[jv][bv] = fmaf(wv[jv].w, x4.w, acc[jv][bv]);
                }
            }
        }
    }
    #pragma unroll
    for (int jv = 0; jv < 2; ++jv)
        #pragma unroll
        for (int bv = 0; bv < 8; ++bv)
            red[jg * 2 + jv][bg * 8 + bv][kg] = acc[jv][bv];
    __syncthreads();
    if (tid < 64) {                                // 2 ch x 32 b
        const int c2 = tid >> 5, b = tid & 31;
        float g4[4];
        #pragma unroll
        for (int gate = 0; gate < 4; ++gate) {
            float s = 0.0f;
            #pragma unroll
            for (int k = 0; k < 16; ++k) s += red[gate * 2 + c2][b][k];
            int row = gate * HD_ + ch0 + c2;
            g4[gate] = s + b_ih[row] + b_hh[row];
        }
        int idx = b * HD_ + ch0 + c2;
        float c1 = sigf(g4[1]) * c_st[idx] + sigf(g4[0]) * tanhf(g4[2]);
        h_out[idx] = sigf(g4[3]) * tanhf(c1);
        c_st[idx] = c1;
    }
}

// ---------------------------------------------------------------- mlp1 relu (256 blocks x 4 j)
__global__ __launch_bounds__(256) void k_mlp1(
    const float* __restrict__ X, const float* __restrict__ W,
    const float* __restrict__ bias, float* __restrict__ out)
{
    __shared__ __align__(16) float Xs[32 * 256];
    __shared__ float red[4][32][17];               // 8.7 KB
    const int tid = threadIdx.x;
    const int kg = tid & 15, jg = (tid >> 4) & 3, bg = tid >> 6;
    const int jbase = blockIdx.x * 4;

    float acc[8];
    #pragma unroll
    for (int bv = 0; bv < 8; ++bv) acc[bv] = 0.0f;

    for (int k0 = 0; k0 < HD_; k0 += 256) {
        __syncthreads();
        #pragma unroll
        for (int i = 0; i < 8; ++i) {
            int lin = tid + i * 256;
            int bb = lin >> 6, q = lin & 63;
            *(float4*)&Xs[bb * 256 + q * 4] = *(const float4*)(X + (size_t)bb * HD_ + k0 + q * 4);
        }
        __syncthreads();
        #pragma unroll
        for (int qq = 0; qq < 4; ++qq) {
            const int qc = kg + qq * 16;
            float4 w4 = *(const float4*)(W + (size_t)(jbase + jg) * HD_ + k0 + qc * 4);
            #pragma unroll
            for (int bv = 0; bv < 8; ++bv) {
                float4 x4 = *(const float4*)&Xs[(bg * 8 + bv) * 256 + qc * 4];
                acc[bv] = fmaf(w4.x, x4.x, acc[bv]);
                acc[bv] = fmaf(w4.y, x4.y, acc[bv]);
                acc[bv] = fmaf(w4.z, x4.z, acc[bv]);
                acc[bv] = fmaf(w4.w, x4.w, acc[bv]);
            }
        }
    }
    #pragma unroll
    for (int bv = 0; bv < 8; ++bv)
        red[jg][bg * 8 + bv][kg] = acc[bv];
    __syncthreads();
    if (tid < 128) {                               // 4 j x 32 b
        int jjo = tid >> 5, b = tid & 31;
        float s = 0.0f;
        #pragma unroll
        for (int k = 0; k < 16; ++k) s += red[jjo][b][k];
        int jo = jbase + jjo;
        out[(size_t)b * HD_ + jo] = fmaxf(s + bias[jo], 0.0f);
    }
}

// ---------------------------------------------------------------- logits GEMM + lmask + per-block argmax partials
__global__ __launch_bounds__(256) void k_logits(
    const float* __restrict__ hid, const float* __restrict__ W2,
    const float* __restrict__ b2, const float* __restrict__ lmask,
    float* __restrict__ lg_out, float* __restrict__ pval, int* __restrict__ pidx)
{
    __shared__ __align__(16) float Xs[32 * 256];
    __shared__ float red[16][32][17];
    const int tid = threadIdx.x;
    const int kg = tid & 15, jg = (tid >> 4) & 3, bg = tid >> 6;
    const int jbase = blockIdx.x * 16;

    float acc[4][8];
    #pragma unroll
    for (int jv = 0; jv < 4; ++jv)
        #pragma unroll
        for (int bv = 0; bv < 8; ++bv) acc[jv][bv] = 0.0f;

    for (int k0 = 0; k0 < HD_; k0 += 256) {
        __syncthreads();
        #pragma unroll
        for (int i = 0; i < 8; ++i) {
            int lin = tid + i * 256;
            int bb = lin >> 6, q = lin & 63;
            *(float4*)&Xs[bb * 256 + q * 4] = *(const float4*)(hid + (size_t)bb * HD_ + k0 + q * 4);
        }
        __syncthreads();
        #pragma unroll
        for (int qq = 0; qq < 4; ++qq) {
            const int qc = kg + qq * 16;
            float4 wv[4];
            #pragma unroll
            for (int jv = 0; jv < 4; ++jv)
                wv[jv] = *(const float4*)(W2 + (size_t)(jbase + jg * 4 + jv) * HD_ + k0 + qc * 4);
            #pragma unroll
            for (int bv = 0; bv < 8; ++bv) {
                float4 x4 = *(const float4*)&Xs[(bg * 8 + bv) * 256 + qc * 4];
                #pragma unroll
                for (int jv = 0; jv < 4; ++jv) {
                    acc[jv][bv] = fmaf(wv[jv].x, x4.x, acc[jv][bv]);
                    acc[jv][bv] = fmaf(wv[jv].y, x4.y, acc[jv][bv]);
                    acc[jv][bv] = fmaf(wv[jv].z, x4.z, acc[jv][bv]);
                    acc[jv][bv] = fmaf(wv[jv].w, x4.w, acc[jv][bv]);
                }
            }
        }
    }
    #pragma unroll
    for (int jv = 0; jv < 4; ++jv)
        #pragma unroll
        for (int bv = 0; bv < 8; ++bv)
            red[jg * 4 + jv][bg * 8 + bv][kg] = acc[jv][bv];
    __syncthreads();
    for (int o = tid; o < 16 * B_; o += 256) {
        int jjo = o >> 5, b = o & 31;
        float s = 0.0f;
        #pragma unroll
        for (int k = 0; k < 16; ++k) s += red[jjo][b][k];
        int jo = jbase + jjo;
        s += b2[jo] + lmask[(size_t)b * N_ + jo];
        lg_out[(size_t)b * (T_ * N_) + jo] = s;
        red[jjo][b][16] = s;
    }
    __syncthreads();
    if (tid < 32) {
        int b = tid;
        float best = -1e38f; int bi = 0;
        #pragma unroll
        for (int jjo = 0; jjo < 16; ++jjo) {
            float v = red[jjo][b][16];
            if (v > best) { best = v; bi = jjo; }   // strict > keeps smallest j on ties
        }
        pval[(size_t)b * NLOGB + blockIdx.x] = best;
        pidx[(size_t)b * NLOGB + blockIdx.x] = jbase + bi;
    }
}

// ---------------------------------------------------------------- argmax merge + lmask update + q = emb[nid]@dense_W^T
__global__ __launch_bounds__(256) void k_merge(
    const float* __restrict__ pval, const int* __restrict__ pidx,
    float* __restrict__ d_out, int t, int* __restrict__ nidbuf,
    float* __restrict__ lmask, const float* __restrict__ emb,
    const float* __restrict__ dense_W, const float* __restrict__ dense_b,
    float* __restrict__ qbuf)
{
    __shared__ float sv[256];
    __shared__ int   si[256];
    __shared__ __align__(16) float lab[ED_];
    const int b = blockIdx.x, tid = threadIdx.x;
    float best = -1e38f; int bi = N_;
    for (int p = tid; p < NLOGB; p += 256) {
        float v = pval[(size_t)b * NLOGB + p];
        int   i = pidx[(size_t)b * NLOGB + p];
        if (v > best || (v == best && i < bi)) { best = v; bi = i; }
    }
    sv[tid] = best; si[tid] = bi;
    __syncthreads();
    for (int s = 128; s > 0; s >>= 1) {
        if (tid < s) {
            float v2 = sv[tid + s]; int i2 = si[tid + s];
            if (v2 > sv[tid] || (v2 == sv[tid] && i2 < si[tid])) { sv[tid] = v2; si[tid] = i2; }
        }
        __syncthreads();
    }
    int nid = si[0];
    if (tid == 0) {
        nidbuf[b] = nid;
        d_out[O_IDS + (size_t)b * T_ + t] = (float)nid;
        lmask[(size_t)b * N_ + nid] = NEG_;
        lmask[(size_t)b * N_] = 0.0f;             // EOS unmask (covers nid==0 too)
    }
    lab[tid] = emb[(size_t)nid * ED_ + tid];
    __syncthreads();
    const float4* Lq = (const float4*)lab;
    #pragma unroll
    for (int jj = 0; jj < 2; ++jj) {
        int j = tid + jj * 256;
        const float4* Wq = (const float4*)(dense_W + (size_t)j * ED_);
        float s0 = 0.0f, s1 = 0.0f, s2 = 0.0f, s3 = 0.0f;
        #pragma unroll
        for (int q = 0; q < 64; q += 4) {
            float4 w0 = Wq[q],   x0 = Lq[q];
            float4 w1 = Wq[q+1], x1 = Lq[q+1];
            float4 w2 = Wq[q+2], x2 = Lq[q+2];
            float4 w3 = Wq[q+3], x3 = Lq[q+3];
            s0 = fmaf(w0.x,x0.x,s0); s0 = fmaf(w0.y,x0.y,s0); s0 = fmaf(w0.z,x0.z,s0); s0 = fmaf(w0.w,x0.w,s0);
            s1 = fmaf(w1.x,x1.x,s1); s1 = fmaf(w1.y,x1.y,s1); s1 = fmaf(w1.z,x1.z,s1); s1 = fmaf(w1.w,x1.w,s1);
            s2 = fmaf(w2.x,x2.x,s2); s2 = fmaf(w2.y,x2.y,s2); s2 = fmaf(w2.z,x2.z,s2); s2 = fmaf(w2.w,x2.w,s2);
            s3 = fmaf(w3.x,x3.x,s3); s3 = fmaf(w3.y,x3.y,s3); s3 = fmaf(w3.z,x3.z,s3); s3 = fmaf(w3.w,x3.w,s3);
        }
        qbuf[(size_t)b * HE_ + j] = dense_b[j] + ((s0 + s1) + (s2 + s3));
    }
}

// ---------------------------------------------------------------- attn pass 1: per 32-s chunk scores + online-softmax partials
__global__ __launch_bounds__(256) void k_attn1(
    const float* __restrict__ qg, const float* __restrict__ enc,
    const float* __restrict__ pad, float* __restrict__ part)
{
    __shared__ __align__(16) float ql[HE_];
    __shared__ float sc_l[32];
    __shared__ float wp_l[32];
    const int b = blockIdx.y, sc = blockIdx.x;
    const int tid = threadIdx.x, lane = tid & 63, w = tid >> 6;
    ql[tid] = qg[(size_t)b * HE_ + tid];
    ql[tid + 256] = qg[(size_t)b * HE_ + tid + 256];
    __syncthreads();

    #pragma unroll
    for (int i = 0; i < 8; ++i) {
        int sl = w + i * 4;
        int s = sc * 32 + sl;
        float v = wave_dot(enc + ((size_t)b * SE_ + s) * HE_, ql, HE_ / 4);
        if (lane == 0) sc_l[sl] = v + pad[b * SE_ + s];
    }
    __syncthreads();

    float m = -1e38f;
    #pragma unroll
    for (int i = 0; i < 32; ++i) m = fmaxf(m, sc_l[i]);
    if (tid < 32) wp_l[tid] = expf(sc_l[tid] - m);
    __syncthreads();
    float esum = 0.0f;
    #pragma unroll
    for (int i = 0; i < 32; ++i) esum += wp_l[i];

    float a0 = 0.0f, a1 = 0.0f;
    for (int i = 0; i < 32; ++i) {
        float wv = wp_l[i];
        const float* er = enc + ((size_t)b * SE_ + sc * 32 + i) * HE_;
        a0 = fmaf(wv, er[tid], a0);
        a1 = fmaf(wv, er[tid + 256], a1);
    }
    float* pb = part + ((size_t)b * 8 + sc) * 516;
    pb[tid] = a0;
    pb[256 + tid] = a1;
    if (tid == 0) { pb[512] = m; pb[513] = esum; }
}

// ---------------------------------------------------------------- attn pass 2 + x build + mq = x@read_W^T (grid 4 x 32)
__global__ __launch_bounds__(256) void k_attn2read(
    const float* __restrict__ part, const float* __restrict__ sent,
    const int* __restrict__ nidbuf, const float* __restrict__ emb,
    const float* __restrict__ read_W, const float* __restrict__ read_b,
    float* __restrict__ xg, float* __restrict__ mqg)
{
    __shared__ float ms[8], es[8];
    __shared__ __align__(16) float xl[EIN_];
    const int qv = blockIdx.x, b = blockIdx.y;
    const int tid = threadIdx.x;
    if (tid < 8) {
        ms[tid] = part[((size_t)b * 8 + tid) * 516 + 512];
        es[tid] = part[((size_t)b * 8 + tid) * 516 + 513];
    }
    __syncthreads();
    float m = -1e38f;
    #pragma unroll
    for (int c = 0; c < 8; ++c) m = fmaxf(m, ms[c]);
    float scale[8];
    float denom = 0.0f;
    #pragma unroll
    for (int c = 0; c < 8; ++c) { scale[c] = expf(ms[c] - m); denom += es[c] * scale[c]; }
    float inv = 1.0f / denom;
    float a0 = 0.0f, a1 = 0.0f;
    #pragma unroll
    for (int c = 0; c < 8; ++c) {
        const float* pb = part + ((size_t)b * 8 + c) * 516;
        a0 = fmaf(scale[c], pb[tid], a0);
        a1 = fmaf(scale[c], pb[256 + tid], a1);
    }
    a0 *= inv; a1 *= inv;
    int nid = nidbuf[b];
    xl[tid]             = emb[(size_t)nid * ED_ + tid];
    xl[ED_ + tid]       = sent[(size_t)b * HE_ + tid]       + a0;
    xl[ED_ + 256 + tid] = sent[(size_t)b * HE_ + 256 + tid] + a1;
    __syncthreads();
    if (qv == 0) {
        float* xr = xg + (size_t)b * EIN_;
        xr[tid] = xl[tid]; xr[tid + 256] = xl[tid + 256]; xr[tid + 512] = xl[tid + 512];
    }
    // mq rows [qv*64, qv*64+64): 4 threads per row, quarter-K each
    const int r = qv * 64 + (tid >> 2), kq = tid & 3;
    const float4* Wq = (const float4*)(read_W + (size_t)r * EIN_ + kq * 192);
    const float4* xq = (const float4*)(xl + kq * 192);
    float s0 = 0.0f, s1 = 0.0f, s2 = 0.0f, s3 = 0.0f;
    #pragma unroll
    for (int q = 0; q < 48; q += 4) {
        float4 w0 = Wq[q],   v0 = xq[q];
        float4 w1 = Wq[q+1], v1 = xq[q+1];
        float4 w2 = Wq[q+2], v2 = xq[q+2];
        float4 w3 = Wq[q+3], v3 = xq[q+3];
        s0 = fmaf(w0.x,v0.x,s0); s0 = fmaf(w0.y,v0.y,s0); s0 = fmaf(w0.z,v0.z,s0); s0 = fmaf(w0.w,v0.w,s0);
        s1 = fmaf(w1.x,v1.x,s1); s1 = fmaf(w1.y,v1.y,s1); s1 = fmaf(w1.z,v1.z,s1); s1 = fmaf(w1.w,v1.w,s1);
        s2 = fmaf(w2.x,v2.x,s2); s2 = fmaf(w2.y,v2.y,s2); s2 = fmaf(w2.z,v2.z,s2); s2 = fmaf(w2.w,v2.w,s2);
        s3 = fmaf(w3.x,v3.x,s3); s3 = fmaf(w3.y,v3.y,s3); s3 = fmaf(w3.z,v3.z,s3); s3 = fmaf(w3.w,v3.w,s3);
    }
    float s = ((s0 + s1) + (s2 + s3));
    s += __shfl_xor(s, 1, 64);
    s += __shfl_xor(s, 2, 64);
    if (kq == 0) mqg[(size_t)b * MD_ + r] = s + read_b[r];
}

// ---------------------------------------------------------------- ksim standalone (final step drain) — grid (16 kt, 32 b)
__global__ __launch_bounds__(256) void k_ksim(
    const float* __restrict__ mqg,
    const float* __restrict__ mem_k, const float* __restrict__ normk,
    float* __restrict__ key_run)
{
    __shared__ __align__(16) float mql[MD_];
    __shared__ float red[256];
    const int b = blockIdx.y, kt = blockIdx.x;    // kt 0..15
    const int tid = threadIdx.x, lane = tid & 63, w = tid >> 6;
    float mv = mqg[(size_t)b * MD_ + tid];
    mql[tid] = mv;
    red[tid] = mv * mv;
    __syncthreads();
    for (int s = 128; s > 0; s >>= 1) { if (tid < s) red[tid] += red[tid + s]; __syncthreads(); }
    float nmq = sqrtf(red[0]);

    int base = kt * 64 + w * 16;
    for (int i = 0; i < 16; ++i) {
        int k = base + i;
        float num = wave_dot(mem_k + ((size_t)b * KE_ + k) * MD_, mql, MD_ / 4);
        if (lane == 0) {
            float cs = num / fmaxf(nmq * normk[b * KE_ + k], EPS_);
            float o = key_run[b * KE_ + k];
            key_run[b * KE_ + k] = fmaxf(o, cs);
        }
    }
}

// ---------------------------------------------------------------- key finalize + key_out
__global__ __launch_bounds__(256) void k_keyfinal(
    float* __restrict__ key_run, const void* __restrict__ kmask, float* __restrict__ d_out)
{
    int idx = blockIdx.x * 256 + threadIdx.x;    // 0..32767
    bool b8 = mask_is_b8(kmask);
    float v = key_run[idx];
    v = (v < 0.0f) ? 0.0f : v;
    key_run[idx] = v;
    d_out[O_KEY + idx] = mask_at(kmask, idx, b8) ? v : -1.0f;
}

// ---------------------------------------------------------------- val contributions (rows gated by bf16 rowmax; exact f32 recompute)
__global__ __launch_bounds__(256) void k_val(
    const float* __restrict__ rowmax, const float* __restrict__ mem_k, const float* __restrict__ mem_v,
    const float* __restrict__ normk, const float* __restrict__ normv,
    const float* __restrict__ key_sim, float* __restrict__ val_sim)
{
    int idx = blockIdx.x * 256 + threadIdx.x;    // 0..32767 : (b,k)
    if (rowmax[idx] < GATE_) return;
    int b = idx >> 10;
    const float* krow = mem_k + (size_t)idx * MD_;
    float nk = normk[idx];
    float ks = key_sim[idx];
    float rm = -1e30f;
    for (int v = 0; v < VE_; ++v) {
        const float* vrow = mem_v + ((size_t)b * VE_ + v) * MD_;
        float d = 0.0f;
        for (int e = 0; e < MD_; ++e) d = fmaf(krow[e], vrow[e], d);
        float cs = d / fmaxf(nk * normv[b * VE_ + v], EPS_);
        rm = fmaxf(rm, cs);
    }
    float thr = fmaxf(rm, SPARSE_);
    for (int v = 0; v < VE_; ++v) {
        const float* vrow = mem_v + ((size_t)b * VE_ + v) * MD_;
        float d = 0.0f;
        for (int e = 0; e < MD_; ++e) d = fmaf(krow[e], vrow[e], d);
        float cs = d / fmaxf(nk * normv[b * VE_ + v], EPS_);
        if (cs >= thr) atomicAdd(&val_sim[(size_t)b * VE_ + v], ks * cs);
    }
}

// ---------------------------------------------------------------- val_out
__global__ __launch_bounds__(256) void k_valout(
    const float* __restrict__ val_sim, const void* __restrict__ vmask, float* __restrict__ d_out)
{
    int idx = blockIdx.x * 256 + threadIdx.x;
    bool b8 = mask_is_b8(vmask);
    d_out[O_VAL + idx] = mask_at(vmask, idx, b8) ? val_sim[idx] : -1.0f;
}

// ================================================================ launch
extern "C" void kernel_launch(void* const* d_in, const int* in_sizes, int n_in,
                              void* d_out_v, int out_size, void* d_ws, size_t ws_size,
                              hipStream_t stream)
{
    const float* enc      = (const float*)d_in[0];
    const float* hidden   = (const float*)d_in[1];
    const float* cell     = (const float*)d_in[2];
    const void*  encmask  = d_in[4];
    const void*  kmask    = d_in[5];
    const float* mem_k    = (const float*)d_in[6];
    const void*  vmask    = d_in[7];
    const float* mem_v    = (const float*)d_in[8];
    const float* W_ih     = (const float*)d_in[9];
    const float* W_hh     = (const float*)d_in[10];
    const float* b_ih     = (const float*)d_in[11];
    const float* b_hh     = (const float*)d_in[12];
    const float* mlp_W1   = (const float*)d_in[13];
    const float* mlp_b1   = (const float*)d_in[14];
    const float* mlp_W2   = (const float*)d_in[15];
    const float* mlp_b2   = (const float*)d_in[16];
    const float* emb      = (const float*)d_in[17];
    const float* dense_W  = (const float*)d_in[18];
    const float* dense_b  = (const float*)d_in[19];
    const float* read_W   = (const float*)d_in[20];
    const float* read_b   = (const float*)d_in[21];
    float* d_out = (float*)d_out_v;
    float* ws = (float*)d_ws;

    float* hA      = ws;             // 32768
    float* hB      = ws + 32768;     // 32768
    float* c       = ws + 65536;     // 32768
    float* x       = ws + 98304;     // 24576
    float* hid     = ws + 122880;    // 32768
    float* lmask   = ws + 155648;    // 262144
    float* sent    = ws + 417792;    // 16384
    float* pad     = ws + 434176;    // 8192
    float* key_run = ws + 442368;    // 32768
    float* val_sim = ws + 475136;    // 32768
    float* normk   = ws + 507904;    // 32768
    float* normv   = ws + 540672;    // 32768
    float* rowmax  = ws + 573440;    // 32768
    int*   nidbuf  = (int*)(ws + 606208); // 64
    float* mqg     = ws + 606272;    // 8192
    float* qbuf    = ws + 614464;    // 16384
    float* part    = ws + 630848;    // 132096
    float* pval    = ws + 762944;    // 16384
    int*   pidx    = (int*)(ws + 779328); // 16384
    // total ≈ 795712 floats ≈ 3.04 MB

    k_init<<<1024, 256, 0, stream>>>(hidden, cell, enc, encmask, hA, c, x, lmask, sent, pad, key_run, val_sim, rowmax);
    k_norms<<<256, 256, 0, stream>>>(mem_k, mem_v, normk, normv);
    k_rowmax_mfma<<<dim3(8, 4, 32), 256, 0, stream>>>(mem_k, mem_v, normk, normv, rowmax);

    const float* hin = hA;
    float* hout = hB;
    for (int t = 0; t < T_; ++t) {
        // gates_t co-launched with ksim_{t-1} (independent; both ready after attn2read_{t-1})
        k_gates_ksim<<<1024, 256, 0, stream>>>(x, W_ih, hin, W_hh, b_ih, b_hh, c, hout,
                                               mqg, mem_k, normk, key_run, t > 0 ? 1 : 0);
        k_mlp1<<<HD_ / 4, 256, 0, stream>>>(hout, mlp_W1, mlp_b1, hid);
        k_logits<<<N_ / 16, 256, 0, stream>>>(hid, mlp_W2, mlp_b2, lmask,
                                              d_out + (size_t)t * N_, pval, pidx);
        k_merge<<<B_, 256, 0, stream>>>(pval, pidx, d_out, t, nidbuf, lmask,
                                        emb, dense_W, dense_b, qbuf);
        k_attn1<<<dim3(8, B_), 256, 0, stream>>>(qbuf, enc, pad, part);
        k_attn2read<<<dim3(4, B_), 256, 0, stream>>>(part, sent, nidbuf, emb, read_W, read_b, x, mqg);
        float* tmp = (float*)hin; hin = hout; hout = tmp;
    }
    // drain ksim for the final step
    k_ksim<<<dim3(16, B_), 256, 0, stream>>>(mqg, mem_k, normk, key_run);

    k_keyfinal<<<128, 256, 0, stream>>>(key_run, kmask, d_out);
    k_val<<<128, 256, 0, stream>>>(rowmax, mem_k, mem_v, normk, normv, key_run, val_sim);
    k_valout<<<128, 256, 0, stream>>>(val_sim, vmask, d_out);
}